// Round 2
// baseline (95565.131 us; speedup 1.0000x reference)
//
#include <hip/hip_runtime.h>

#define Tn 512
#define Bn 512
#define Fn 128
#define Gn 12
#define Hn 768
#define XW 140   // F+G
#define D1n 512
#define An 128
#define NT 512
#define NB 512

using bfrag  = __attribute__((ext_vector_type(8))) short;   // 8 bf16
using f32x4  = __attribute__((ext_vector_type(4))) float;
using short8 = __attribute__((ext_vector_type(8))) short;
using short4v= __attribute__((ext_vector_type(4))) short;
using float4v= __attribute__((ext_vector_type(4))) float;

static const size_t HSTR = (size_t)Bn * Hn;   // 393216

__device__ __forceinline__ unsigned short f2bf(float x) {
  union { float f; unsigned int u; } v; v.f = x;
  unsigned int r = v.u + 0x7FFFu + ((v.u >> 16) & 1u);   // RNE
  return (unsigned short)(r >> 16);
}
__device__ __forceinline__ float bf2f(unsigned short h) {
  union { unsigned int u; float f; } v; v.u = ((unsigned int)h) << 16; return v.f;
}
__device__ __forceinline__ float sigmoid_f(float x) { return 1.f / (1.f + __expf(-x)); }
__device__ __forceinline__ float tanh_f(float x) {
  x = fminf(fmaxf(x, -15.f), 15.f);
  float e = __expf(2.f * x);
  return (e - 1.f) / (e + 1.f);
}
__device__ __forceinline__ f32x4 MFMA(bfrag a, bfrag b, f32x4 c) {
  return __builtin_amdgcn_mfma_f32_16x16x32_bf16(a, b, c, 0, 0, 0);
}

// ---------------- two-level grid barrier (512 blocks resident: 8 subs x 64) ----------------
__device__ __forceinline__ void grid_barrier(int* barb) {
  __syncthreads();
  if (threadIdx.x == 0) {
    __threadfence();
    int* gen  = barb + 288;
    int* root = barb + 256;
    int* subc = barb + ((blockIdx.x & 7) << 5);
    int g = __hip_atomic_load(gen, __ATOMIC_RELAXED, __HIP_MEMORY_SCOPE_AGENT);
    int prev = __hip_atomic_fetch_add(subc, 1, __ATOMIC_ACQ_REL, __HIP_MEMORY_SCOPE_AGENT);
    if (prev == 63) {
      __hip_atomic_store(subc, 0, __ATOMIC_RELAXED, __HIP_MEMORY_SCOPE_AGENT);
      int rprev = __hip_atomic_fetch_add(root, 1, __ATOMIC_ACQ_REL, __HIP_MEMORY_SCOPE_AGENT);
      if (rprev == 7) {
        __hip_atomic_store(root, 0, __ATOMIC_RELAXED, __HIP_MEMORY_SCOPE_AGENT);
        __hip_atomic_store(gen, g + 1, __ATOMIC_RELEASE, __HIP_MEMORY_SCOPE_AGENT);
      } else {
        while (__hip_atomic_load(gen, __ATOMIC_RELAXED, __HIP_MEMORY_SCOPE_AGENT) == g)
          __builtin_amdgcn_s_sleep(2);
      }
    } else {
      while (__hip_atomic_load(gen, __ATOMIC_RELAXED, __HIP_MEMORY_SCOPE_AGENT) == g)
        __builtin_amdgcn_s_sleep(2);
    }
    __threadfence();
  }
  __syncthreads();
}

// ---------------- setup ----------------
struct SetupP {
  const float *Wih1f, *Whh1f, *Wih2f, *Whh2f, *l1wf, *l2wf, *bih1, *bhh1, *bih2, *bhh2;
  unsigned short *Wih1, *Whh1, *Wih2, *Whh2, *l1w, *l2w;
  float *b1s, *b2s;
  unsigned short *h1, *h2;
  float *c1, *c2;
  int* bar;
};

__global__ void setup_kernel(SetupP sp) {
  const size_t gtid = (size_t)blockIdx.x * blockDim.x + threadIdx.x;
  const size_t gs = (size_t)gridDim.x * blockDim.x;
  for (size_t i = gtid; i < 3072u*128u; i += gs) sp.Wih1[i] = f2bf(sp.Wih1f[i]);
  for (size_t i = gtid; i < 3072u*768u; i += gs) sp.Whh1[i] = f2bf(sp.Whh1f[i]);
  for (size_t i = gtid; i < 3072u*768u; i += gs) sp.Wih2[i] = f2bf(sp.Wih2f[i]);
  for (size_t i = gtid; i < 3072u*768u; i += gs) sp.Whh2[i] = f2bf(sp.Whh2f[i]);
  for (size_t i = gtid; i < 512u*768u; i += gs) {
    size_t c = i / 768u, k = i - c * 768u;
    sp.l1w[i] = f2bf(sp.l1wf[c * 780u + k]);
  }
  for (size_t i = gtid; i < 128u*512u; i += gs) sp.l2w[i] = f2bf(sp.l2wf[i]);
  for (size_t i = gtid; i < 3072u; i += gs) {
    sp.b1s[i] = sp.bih1[i] + sp.bhh1[i];
    sp.b2s[i] = sp.bih2[i] + sp.bhh2[i];
  }
  for (size_t i = gtid; i < 4u*HSTR; i += gs) { sp.h1[i] = 0; sp.h2[i] = 0; }
  for (size_t i = gtid; i < HSTR; i += gs) { sp.c1[i] = 0.f; sp.c2[i] = 0.f; }
  for (size_t i = gtid; i < 512u; i += gs) sp.bar[i] = 0;
}

// ---------------- main persistent kernel ----------------
struct MainP {
  const float* x;
  const float* l1w_f; const float* l1b; const float* l2b;
  const unsigned short *Wih1, *Whh1, *Wih2, *Whh2, *l1w, *l2w;
  const float *b1s, *b2s;
  unsigned short *h1, *h2, *a1hi, *a1lo;
  float *c1, *c2, *out;
  int* bar;
};

// stage a 16-row x 768-col hi/lo tile into LDS with 16B-granule XOR swizzle
__device__ __forceinline__ void stage_h16(char* smem, const unsigned short* hi_src,
    const unsigned short* lo_src, int rb, int tid) {
  #pragma unroll
  for (int it = 0; it < 6; ++it) {
    int G = tid + it * NT;           // 0..3071
    int hl = (G >= 1536) ? 1 : 0;
    int G2 = G - (hl ? 1536 : 0);
    int r = G2 / 96;
    int gq = G2 - r * 96;
    const unsigned short* src = (hl ? lo_src : hi_src) + (size_t)(rb + r) * Hn + gq * 8;
    short8 v = *(const short8*)src;
    *(short8*)(smem + hl * 24576 + r * 1536 + ((gq ^ (r & 7)) << 4)) = v;
  }
}

// gates MFMA: A from LDS (hi at 0, lo at 24576), 3 B column-frags direct from global
__device__ __forceinline__ void gate_mfma(const char* smem, int rstride,
    const unsigned short* b0p, const unsigned short* b1p, const unsigned short* b2p,
    int kbeg, int kend, int lr, int lk,
    f32x4& A0, f32x4& A1, f32x4& A2) {
  #pragma unroll 4
  for (int kb = kbeg; kb < kend; kb += 32) {
    int gi = (kb >> 3) + lk;
    int aoff = lr * rstride + ((gi ^ (lr & 7)) << 4);
    bfrag ahi = *(const bfrag*)(smem + aoff);
    bfrag alo = *(const bfrag*)(smem + 24576 + aoff);
    bfrag b0 = *(const bfrag*)(b0p + kb + lk * 8);
    bfrag b1 = *(const bfrag*)(b1p + kb + lk * 8);
    bfrag b2 = *(const bfrag*)(b2p + kb + lk * 8);
    A0 = MFMA(ahi, b0, A0); A0 = MFMA(alo, b0, A0);
    A1 = MFMA(ahi, b1, A1); A1 = MFMA(alo, b1, A1);
    A2 = MFMA(ahi, b2, A2); A2 = MFMA(alo, b2, A2);
  }
}

// elementwise LSTM cell: reads gbuf (2 K-halves x 4 gates x 16 x 48) from LDS
__device__ __forceinline__ void cell_phase(const char* smem, const float* bsum,
    float* cbuf, unsigned short* h_hi, unsigned short* h_lo,
    int rb, int ub48, int tid) {
  if (tid < 192) {
    int r = tid / 12, q = tid - (tid / 12) * 12;
    int u0 = q * 4;
    const float* gb = (const float*)smem;
    size_t rowb = (size_t)(rb + r) * Hn + ub48 + u0;
    float4v c4 = *(const float4v*)(cbuf + rowb);
    float4v c4o; short4v hv, lv;
    #pragma unroll
    for (int j = 0; j < 4; ++j) {
      int u = u0 + j; int gu = ub48 + u;
      float gi = gb[(0*16 + r)*48 + u] + gb[(4*16 + r)*48 + u] + bsum[gu];
      float gf = gb[(1*16 + r)*48 + u] + gb[(5*16 + r)*48 + u] + bsum[Hn + gu];
      float gg = gb[(2*16 + r)*48 + u] + gb[(6*16 + r)*48 + u] + bsum[2*Hn + gu];
      float go = gb[(3*16 + r)*48 + u] + gb[(7*16 + r)*48 + u] + bsum[3*Hn + gu];
      float cn = sigmoid_f(gf) * c4[j] + sigmoid_f(gi) * tanh_f(gg);
      float hn = sigmoid_f(go) * tanh_f(cn);
      c4o[j] = cn;
      unsigned short h = f2bf(hn);
      hv[j] = (short)h;
      lv[j] = (short)f2bf(hn - bf2f(h));
    }
    *(float4v*)(cbuf + rowb) = c4o;
    *(short4v*)(h_hi + rowb) = hv;
    *(short4v*)(h_lo + rowb) = lv;
  }
}

__global__ __launch_bounds__(NT, 4) void lstm_main(MainP P) {
  const int tid = threadIdx.x;
  const int bid = blockIdx.x;
  const int lane = tid & 63;
  const int wv = tid >> 6;          // 0..7
  const int lr = lane & 15;
  const int lk = lane >> 4;         // 0..3

  __shared__ __align__(16) char smem[49152];

  const int rb  = (bid >> 4) * 16;  // 32 row-tiles of 16 rows
  const int CT  = bid & 15;         // 16 col-tiles
  const int ub48 = CT * 48;
  const int cb3 = CT * 32;
  const int cb4 = CT * 8;
  const int g  = wv & 3;            // gate (P1/P2)
  const int kh = wv >> 2;           // K-half (P1/P2)
  const int ch = wv & 1;            // col-half (P3)
  const int kq3 = wv >> 1;          // K-quarter (P3)

  for (int t = 0; t < Tn; ++t) {
    const int p = t & 1;
    const unsigned short* h1hi_r = P.h1 + (size_t)(p*2+0) * HSTR;
    const unsigned short* h1lo_r = P.h1 + (size_t)(p*2+1) * HSTR;
    unsigned short* h1hi_w = P.h1 + (size_t)((p^1)*2+0) * HSTR;
    unsigned short* h1lo_w = P.h1 + (size_t)((p^1)*2+1) * HSTR;
    const unsigned short* h2hi_r = P.h2 + (size_t)(p*2+0) * HSTR;
    const unsigned short* h2lo_r = P.h2 + (size_t)(p*2+1) * HSTR;
    unsigned short* h2hi_w = P.h2 + (size_t)((p^1)*2+0) * HSTR;
    unsigned short* h2lo_w = P.h2 + (size_t)((p^1)*2+1) * HSTR;

    // ================= PHASE 1 =================
    // stage x (fp32 -> hi/lo bf16), 16 rows x 128 cols, swizzled
    {
      int r = tid >> 5, q = tid & 31;          // quad of 4 floats
      const float* xp = P.x + ((size_t)t * Bn + rb + r) * XW + q * 4;
      float4v v = *(const float4v*)xp;
      short4v hv, lv;
      #pragma unroll
      for (int j = 0; j < 4; ++j) {
        unsigned short h = f2bf(v[j]);
        hv[j] = (short)h;
        lv[j] = (short)f2bf(v[j] - bf2f(h));
      }
      int gq = q >> 1, hs = (q & 1) * 8;
      int off = r * 256 + ((gq ^ (r & 7)) << 4) + hs;
      *(short4v*)(smem + off) = hv;
      *(short4v*)(smem + 24576 + off) = lv;
    }
    __syncthreads();

    f32x4 A0 = {0.f,0.f,0.f,0.f}, A1 = {0.f,0.f,0.f,0.f}, A2 = {0.f,0.f,0.f,0.f};
    {
      const unsigned short* w0 = P.Wih1 + (size_t)(g * Hn + ub48 + lr) * Fn;
      gate_mfma(smem, 256, w0, w0 + (size_t)16*Fn, w0 + (size_t)32*Fn,
                kh * 64, kh * 64 + 64, lr, lk, A0, A1, A2);
    }
    __syncthreads();
    stage_h16(smem, h1hi_r, h1lo_r, rb, tid);
    __syncthreads();
    {
      const unsigned short* w0 = P.Whh1 + (size_t)(g * Hn + ub48 + lr) * Hn;
      gate_mfma(smem, 1536, w0, w0 + (size_t)16*Hn, w0 + (size_t)32*Hn,
                kh * 384, kh * 384 + 384, lr, lk, A0, A1, A2);
    }
    __syncthreads();
    {
      float* gb = (float*)smem;
      int base = ((kh * 4 + g) * 16 + lk * 4) * 48 + lr;
      #pragma unroll
      for (int j = 0; j < 4; ++j) {
        gb[base + j*48]      = A0[j];
        gb[base + j*48 + 16] = A1[j];
        gb[base + j*48 + 32] = A2[j];
      }
    }
    __syncthreads();
    cell_phase(smem, P.b1s, P.c1, h1hi_w, h1lo_w, rb, ub48, tid);
    grid_barrier(P.bar);

    // ================= PHASE 2 =================
    A0 = (f32x4){0.f,0.f,0.f,0.f}; A1 = A0; A2 = A0;
    stage_h16(smem, h1hi_w, h1lo_w, rb, tid);   // current h1
    __syncthreads();
    {
      const unsigned short* w0 = P.Wih2 + (size_t)(g * Hn + ub48 + lr) * Hn;
      gate_mfma(smem, 1536, w0, w0 + (size_t)16*Hn, w0 + (size_t)32*Hn,
                kh * 384, kh * 384 + 384, lr, lk, A0, A1, A2);
    }
    __syncthreads();
    stage_h16(smem, h2hi_r, h2lo_r, rb, tid);   // previous h2
    __syncthreads();
    {
      const unsigned short* w0 = P.Whh2 + (size_t)(g * Hn + ub48 + lr) * Hn;
      gate_mfma(smem, 1536, w0, w0 + (size_t)16*Hn, w0 + (size_t)32*Hn,
                kh * 384, kh * 384 + 384, lr, lk, A0, A1, A2);
    }
    __syncthreads();
    {
      float* gb = (float*)smem;
      int base = ((kh * 4 + g) * 16 + lk * 4) * 48 + lr;
      #pragma unroll
      for (int j = 0; j < 4; ++j) {
        gb[base + j*48]      = A0[j];
        gb[base + j*48 + 16] = A1[j];
        gb[base + j*48 + 32] = A2[j];
      }
    }
    __syncthreads();
    cell_phase(smem, P.b2s, P.c2, h2hi_w, h2lo_w, rb, ub48, tid);
    grid_barrier(P.bar);

    // ================= PHASE 3: l1 + selu -> a1 =================
    stage_h16(smem, h2hi_w, h2lo_w, rb, tid);   // current h2
    __syncthreads();
    f32x4 a3 = {0.f,0.f,0.f,0.f};
    {
      const unsigned short* wl = P.l1w + (size_t)(cb3 + ch * 16 + lr) * Hn;
      #pragma unroll 3
      for (int kb = kq3 * 192; kb < kq3 * 192 + 192; kb += 32) {
        int gi = (kb >> 3) + lk;
        int aoff = lr * 1536 + ((gi ^ (lr & 7)) << 4);
        bfrag ahi = *(const bfrag*)(smem + aoff);
        bfrag alo = *(const bfrag*)(smem + 24576 + aoff);
        bfrag bw = *(const bfrag*)(wl + kb + lk * 8);
        a3 = MFMA(ahi, bw, a3); a3 = MFMA(alo, bw, a3);
      }
    }
    __syncthreads();
    {
      float* s3 = (float*)smem;
      int b3 = ((kq3 * 2 + ch) * 16 + lk * 4) * 16 + lr;
      #pragma unroll
      for (int j = 0; j < 4; ++j) s3[b3 + j * 16] = a3[j];
    }
    __syncthreads();
    if (tid < 128) {
      const float* s3 = (const float*)smem;
      int r = tid >> 3, q = tid & 7;
      int row = rb + r;
      const float* xg = P.x + ((size_t)t * Bn + row) * XW + Fn;
      float xgv[Gn];
      #pragma unroll
      for (int qq = 0; qq < Gn; ++qq) xgv[qq] = xg[qq];
      short4v hv, lv;
      #pragma unroll
      for (int j = 0; j < 4; ++j) {
        int cl = q * 4 + j;
        int col = cb3 + cl;
        float v = P.l1b[col];
        #pragma unroll
        for (int kq = 0; kq < 4; ++kq)
          v += s3[((kq * 2 + (cl >> 4)) * 16 + r) * 16 + (cl & 15)];
        const float* wg = P.l1w_f + (size_t)col * 780 + 768;
        #pragma unroll
        for (int qq = 0; qq < Gn; ++qq) v += xgv[qq] * wg[qq];
        float s = (v > 0.f) ? 1.0507009873554805f * v
                            : 1.7580993408473766f * (__expf(v) - 1.f);
        unsigned short h = f2bf(s);
        hv[j] = (short)h;
        lv[j] = (short)f2bf(s - bf2f(h));
      }
      size_t ob = (size_t)row * D1n + cb3 + q * 4;
      *(short4v*)(P.a1hi + ob) = hv;
      *(short4v*)(P.a1lo + ob) = lv;
    }
    grid_barrier(P.bar);

    // ================= PHASE 4: l2 -> out[t] =================
    // stage a1 tile: 16 rows x 512, hi/lo, swizzled (row stride 1024B)
    {
      #pragma unroll
      for (int it = 0; it < 4; ++it) {
        int G = tid + it * NT;           // 0..2047
        int hl = (G >= 1024) ? 1 : 0;
        int G2 = G - (hl ? 1024 : 0);
        int r = G2 >> 6, gq = G2 & 63;
        const unsigned short* src = (hl ? P.a1lo : P.a1hi) + (size_t)(rb + r) * D1n + gq * 8;
        short8 v = *(const short8*)src;
        *(short8*)(smem + hl * 24576 + r * 1024 + ((gq ^ (r & 7)) << 4)) = v;
      }
    }
    __syncthreads();
    f32x4 a4 = {0.f,0.f,0.f,0.f};
    {
      int wcol = cb4 + lr; if (wcol > 127) wcol = 127;
      const unsigned short* w2 = P.l2w + (size_t)wcol * D1n;
      #pragma unroll
      for (int kb = wv * 64; kb < wv * 64 + 64; kb += 32) {
        int gi = (kb >> 3) + lk;
        int aoff = lr * 1024 + ((gi ^ (lr & 7)) << 4);
        bfrag ahi = *(const bfrag*)(smem + aoff);
        bfrag alo = *(const bfrag*)(smem + 24576 + aoff);
        bfrag bw = *(const bfrag*)(w2 + kb + lk * 8);
        a4 = MFMA(ahi, bw, a4); a4 = MFMA(alo, bw, a4);
      }
    }
    __syncthreads();
    {
      float* sr = (float*)smem;
      int b4 = (wv * 16 + lk * 4) * 16 + lr;
      #pragma unroll
      for (int j = 0; j < 4; ++j) sr[b4 + j * 16] = a4[j];
    }
    __syncthreads();
    if (tid < 128) {
      const float* sr = (const float*)smem;
      int r = tid >> 3, cl = tid & 7;
      float v = P.l2b[cb4 + cl];
      #pragma unroll
      for (int w = 0; w < 8; ++w) v += sr[(w * 16 + r) * 16 + cl];
      P.out[(size_t)t * (Bn * An) + (size_t)(rb + r) * An + cb4 + cl] = v;
    }
    __syncthreads();
  }
}

// ---------------- launch ----------------
extern "C" void kernel_launch(void* const* d_in, const int* in_sizes, int n_in,
                              void* d_out, int out_size, void* d_ws, size_t ws_size,
                              hipStream_t stream) {
  const float* x     = (const float*)d_in[0];
  const float* Wih1f = (const float*)d_in[1];
  const float* Whh1f = (const float*)d_in[2];
  const float* bih1  = (const float*)d_in[3];
  const float* bhh1  = (const float*)d_in[4];
  const float* Wih2f = (const float*)d_in[5];
  const float* Whh2f = (const float*)d_in[6];
  const float* bih2  = (const float*)d_in[7];
  const float* bhh2  = (const float*)d_in[8];
  const float* l1wf  = (const float*)d_in[9];
  const float* l1b   = (const float*)d_in[10];
  const float* l2wf  = (const float*)d_in[11];
  const float* l2b   = (const float*)d_in[12];

  char* ws = (char*)d_ws;
  constexpr size_t o_Wih1 = 0;
  constexpr size_t o_Whh1 = o_Wih1 + (size_t)3072 * 128 * 2;
  constexpr size_t o_Wih2 = o_Whh1 + (size_t)3072 * 768 * 2;
  constexpr size_t o_Whh2 = o_Wih2 + (size_t)3072 * 768 * 2;
  constexpr size_t o_l1w  = o_Whh2 + (size_t)3072 * 768 * 2;
  constexpr size_t o_l2w  = o_l1w + (size_t)512 * 768 * 2;
  constexpr size_t o_b1s  = o_l2w + (size_t)128 * 512 * 2;
  constexpr size_t o_b2s  = o_b1s + (size_t)3072 * 4;
  constexpr size_t o_h1   = o_b2s + (size_t)3072 * 4;
  constexpr size_t o_h2   = o_h1 + (size_t)4 * 512 * 768 * 2;   // 2 parity x 2 hl
  constexpr size_t o_c1   = o_h2 + (size_t)4 * 512 * 768 * 2;
  constexpr size_t o_c2   = o_c1 + (size_t)512 * 768 * 4;
  constexpr size_t o_a1hi = o_c2 + (size_t)512 * 768 * 4;
  constexpr size_t o_a1lo = o_a1hi + (size_t)512 * 512 * 2;
  constexpr size_t o_bar  = o_a1lo + (size_t)512 * 512 * 2;

  SetupP sp;
  sp.Wih1f = Wih1f; sp.Whh1f = Whh1f; sp.Wih2f = Wih2f; sp.Whh2f = Whh2f;
  sp.l1wf = l1wf; sp.l2wf = l2wf; sp.bih1 = bih1; sp.bhh1 = bhh1; sp.bih2 = bih2; sp.bhh2 = bhh2;
  sp.Wih1 = (unsigned short*)(ws + o_Wih1);
  sp.Whh1 = (unsigned short*)(ws + o_Whh1);
  sp.Wih2 = (unsigned short*)(ws + o_Wih2);
  sp.Whh2 = (unsigned short*)(ws + o_Whh2);
  sp.l1w  = (unsigned short*)(ws + o_l1w);
  sp.l2w  = (unsigned short*)(ws + o_l2w);
  sp.b1s  = (float*)(ws + o_b1s);
  sp.b2s  = (float*)(ws + o_b2s);
  sp.h1   = (unsigned short*)(ws + o_h1);
  sp.h2   = (unsigned short*)(ws + o_h2);
  sp.c1   = (float*)(ws + o_c1);
  sp.c2   = (float*)(ws + o_c2);
  sp.bar  = (int*)(ws + o_bar);
  setup_kernel<<<2048, 256, 0, stream>>>(sp);

  MainP mp;
  mp.x = x; mp.l1w_f = l1wf; mp.l1b = l1b; mp.l2b = l2b;
  mp.Wih1 = sp.Wih1; mp.Whh1 = sp.Whh1; mp.Wih2 = sp.Wih2; mp.Whh2 = sp.Whh2;
  mp.l1w = sp.l1w; mp.l2w = sp.l2w;
  mp.b1s = sp.b1s; mp.b2s = sp.b2s;
  mp.h1 = sp.h1; mp.h2 = sp.h2;
  mp.a1hi = (unsigned short*)(ws + o_a1hi);
  mp.a1lo = (unsigned short*)(ws + o_a1lo);
  mp.c1 = sp.c1; mp.c2 = sp.c2;
  mp.out = (float*)d_out;
  mp.bar = sp.bar;
  lstm_main<<<NB, NT, 0, stream>>>(mp);
}

// Round 3
// 57279.041 us; speedup vs baseline: 1.6684x; 1.6684x over previous
//
#include <hip/hip_runtime.h>

#define Tn 512
#define Bn 512
#define Fn 128
#define Gn 12
#define Hn 768
#define XW 140   // F+G
#define D1n 512
#define An 128
#define NT 512
#define NB 256
#define NGRP 16
#define NMEM 16
#define MROWS 32
#define UPM 48

// LDS layout (dynamic, 99328 B)
#define XOFF 0        // x stage: 32 rows x 256B hi, lo at +8192  (16KB) -- also a1-hi overlap
#define HOFF 16384    // h half-stage: 32 x 768B hi, lo at +24576 (48KB) -> [16384,65536)
#define OOFF 65536    // own-h2: hi 4KB, lo 4KB -> [65536,73728)
#define GOFF 73728    // gbuf fp32 [32][200] = 25600B -> [73728,99328)
#define SMEM_BYTES 99328

using bfrag  = __attribute__((ext_vector_type(8))) short;
using f32x4  = __attribute__((ext_vector_type(4))) float;
using short8 = __attribute__((ext_vector_type(8))) short;
using short4v= __attribute__((ext_vector_type(4))) short;
using float4v= __attribute__((ext_vector_type(4))) float;

static const size_t HSTR = (size_t)Bn * Hn;   // 393216

__device__ __forceinline__ unsigned short f2bf(float x) {
  union { float f; unsigned int u; } v; v.f = x;
  unsigned int r = v.u + 0x7FFFu + ((v.u >> 16) & 1u);
  return (unsigned short)(r >> 16);
}
__device__ __forceinline__ float bf2f(unsigned short h) {
  union { unsigned int u; float f; } v; v.u = ((unsigned int)h) << 16; return v.f;
}
__device__ __forceinline__ float sigmoid_f(float x) { return 1.f / (1.f + __expf(-x)); }
__device__ __forceinline__ float tanh_f(float x) {
  x = fminf(fmaxf(x, -15.f), 15.f);
  float e = __expf(2.f * x);
  return (e - 1.f) / (e + 1.f);
}
__device__ __forceinline__ f32x4 MFMA(bfrag a, bfrag b, f32x4 c) {
  return __builtin_amdgcn_mfma_f32_16x16x32_bf16(a, b, c, 0, 0, 0);
}

// ---------------- group-local flag barrier (16 members, no RMW) ----------------
__device__ __forceinline__ void group_bar(int* flags, int fbase, int member, int target) {
  __syncthreads();                       // all waves' stores drained to L2
  if (threadIdx.x == 0) {
    __threadfence();                     // push dirty L2 -> LLC (cross-XCD visibility)
    __hip_atomic_store(flags + (size_t)(fbase + member) * 32, target,
                       __ATOMIC_RELEASE, __HIP_MEMORY_SCOPE_AGENT);
  }
  if (threadIdx.x < NMEM) {
    while (__hip_atomic_load(flags + (size_t)(fbase + threadIdx.x) * 32,
                             __ATOMIC_RELAXED, __HIP_MEMORY_SCOPE_AGENT) < target)
      __builtin_amdgcn_s_sleep(1);
    __threadfence();                     // invalidate stale L1/L2 before reads
  }
  __syncthreads();
}

// ---------------- setup ----------------
struct SetupP {
  const float *Wih1f, *Whh1f, *Wih2f, *Whh2f, *l1wf, *l2wf, *bih1, *bhh1, *bih2, *bhh2;
  unsigned short *Wih1, *Whh1, *Wih2, *Whh2, *l1wp, *l2wb;
  float *b1s, *b2s;
  unsigned short *h1, *h2;
  int* flags;
};

__global__ void setup_kernel(SetupP sp) {
  const size_t gtid = (size_t)blockIdx.x * blockDim.x + threadIdx.x;
  const size_t gs = (size_t)gridDim.x * blockDim.x;
  for (size_t i = gtid; i < 3072u*128u; i += gs) sp.Wih1[i] = f2bf(sp.Wih1f[i]);
  for (size_t i = gtid; i < 3072u*768u; i += gs) sp.Whh1[i] = f2bf(sp.Whh1f[i]);
  for (size_t i = gtid; i < 3072u*768u; i += gs) sp.Wih2[i] = f2bf(sp.Wih2f[i]);
  for (size_t i = gtid; i < 3072u*768u; i += gs) sp.Whh2[i] = f2bf(sp.Whh2f[i]);
  // padded l1w: [512 cols][16 members * 64], k<48 real else 0
  for (size_t i = gtid; i < 512u*1024u; i += gs) {
    size_t c = i >> 10, k = i & 1023, mm = k >> 6, kk = k & 63;
    sp.l1wp[i] = (kk < 48u) ? f2bf(sp.l1wf[c * 780u + mm * 48u + kk]) : (unsigned short)0;
  }
  for (size_t i = gtid; i < 128u*512u; i += gs) sp.l2wb[i] = f2bf(sp.l2wf[i]);
  for (size_t i = gtid; i < 3072u; i += gs) {
    sp.b1s[i] = sp.bih1[i] + sp.bhh1[i];
    sp.b2s[i] = sp.bih2[i] + sp.bhh2[i];
  }
  for (size_t i = gtid; i < 4u*HSTR; i += gs) { sp.h1[i] = 0; sp.h2[i] = 0; }
  for (size_t i = gtid; i < 8192u; i += gs) sp.flags[i] = 0;
}

// ---------------- main ----------------
struct MainP {
  const float* x;
  const float *l1w_f, *l1b, *l2b;
  const unsigned short *Wih1, *Whh1, *Wih2, *Whh2, *l1wp, *l2wb;
  const float *b1s, *b2s;
  unsigned short *h1, *h2, *a1hi, *a1lo;
  float *zp, *out;
  int* flags;
};

__device__ __forceinline__ void stage_x(const MainP& P, char* smem, int t, int grow0, int tid) {
  int r = tid >> 4, c0 = (tid & 15) * 8;
  const float* xp = P.x + ((size_t)t * Bn + grow0 + r) * XW + c0;
  float4v v0 = *(const float4v*)xp;
  float4v v1 = *(const float4v*)(xp + 4);
  short8 hv, lv;
  #pragma unroll
  for (int j = 0; j < 4; ++j) {
    unsigned short h = f2bf(v0[j]); hv[j] = (short)h; lv[j] = (short)f2bf(v0[j] - bf2f(h));
  }
  #pragma unroll
  for (int j = 0; j < 4; ++j) {
    unsigned short h = f2bf(v1[j]); hv[4+j] = (short)h; lv[4+j] = (short)f2bf(v1[j] - bf2f(h));
  }
  int g = tid & 15;
  int off = r * 256 + ((g ^ (r & 7)) << 4);
  *(short8*)(smem + XOFF + off) = hv;
  *(short8*)(smem + XOFF + 8192 + off) = lv;
}

__device__ __forceinline__ void stage_h(char* smem, const unsigned short* hsrc_hi,
    const unsigned short* hsrc_lo, int grow0, int koff, int tid) {
  #pragma unroll
  for (int it = 0; it < 6; ++it) {
    int idx = tid + it * NT;           // 0..3071
    int hl = (idx >= 1536) ? 1 : 0;
    int i2 = hl ? idx - 1536 : idx;
    int r = i2 / 48, gq = i2 - r * 48;
    const unsigned short* src = (hl ? hsrc_lo : hsrc_hi) + (size_t)(grow0 + r) * Hn + koff + gq * 8;
    short8 v = *(const short8*)src;
    *(short8*)(smem + HOFF + hl * 24576 + r * 768 + ((gq ^ (r & 7)) << 4)) = v;
  }
}

// gates x-part: K=128 from x-region
__device__ __forceinline__ void mfma_x4(const char* smem, const unsigned short* bp, int rr, int lk,
                                        f32x4& A0, f32x4& A1, f32x4& A2) {
  const int rsw = rr & 7;
  const char* ax = smem + XOFF + rr * 256;
  #pragma unroll
  for (int kk = 0; kk < 4; ++kk) {
    int kg = kk * 4 + lk;
    int ao = ((kg ^ rsw) << 4);
    bfrag ahi = *(const bfrag*)(ax + ao);
    bfrag alo = *(const bfrag*)(ax + 8192 + ao);
    bfrag b0 = *(const bfrag*)(bp + kk * 32 + lk * 8);
    bfrag b1 = *(const bfrag*)(bp + 16 * 128 + kk * 32 + lk * 8);
    bfrag b2 = *(const bfrag*)(bp + 32 * 128 + kk * 32 + lk * 8);
    A0 = MFMA(ahi, b0, A0); A0 = MFMA(alo, b0, A0);
    A1 = MFMA(ahi, b1, A1); A1 = MFMA(alo, b1, A1);
    A2 = MFMA(ahi, b2, A2); A2 = MFMA(alo, b2, A2);
  }
}

// gates h-part: 12 K-iters (384 units) from H-region; bp already offset by koff
__device__ __forceinline__ void mfma_h12(const char* smem, const unsigned short* bp, int rr, int lk,
                                         f32x4& A0, f32x4& A1, f32x4& A2) {
  const int rsw = rr & 7;
  const char* ah = smem + HOFF + rr * 768;
  #pragma unroll 4
  for (int kk = 0; kk < 12; ++kk) {
    int kg = kk * 4 + lk;
    int ao = ((kg ^ rsw) << 4);
    bfrag ahi = *(const bfrag*)(ah + ao);
    bfrag alo = *(const bfrag*)(ah + 24576 + ao);
    bfrag b0 = *(const bfrag*)(bp + kk * 32 + lk * 8);
    bfrag b1 = *(const bfrag*)(bp + 16 * 768 + kk * 32 + lk * 8);
    bfrag b2 = *(const bfrag*)(bp + 32 * 768 + kk * 32 + lk * 8);
    A0 = MFMA(ahi, b0, A0); A0 = MFMA(alo, b0, A0);
    A1 = MFMA(ahi, b1, A1); A1 = MFMA(alo, b1, A1);
    A2 = MFMA(ahi, b2, A2); A2 = MFMA(alo, b2, A2);
  }
}

__device__ __forceinline__ void write_gbuf(char* smem, const f32x4& A0, const f32x4& A1,
                                           const f32x4& A2, int rf, int q, int lr, int lk) {
  float* gb = (float*)(smem + GOFF);
  int base = (rf * 16 + lk * 4) * 200 + q * 48 + lr;
  #pragma unroll
  for (int j = 0; j < 4; ++j) {
    gb[base + j * 200]      = A0[j];
    gb[base + j * 200 + 16] = A1[j];
    gb[base + j * 200 + 32] = A2[j];
  }
}

// LSTM cell: 384 threads, c in registers; optional own-h2 LDS mirror (cell2)
__device__ __forceinline__ void cell_do(const char* smem, const float* bsum,
    float4v& creg, unsigned short* hhi, unsigned short* hlo,
    int grow0, int m, int tid, char* ownh2) {
  if (tid < 384) {
    const float* gb = (const float*)(smem + GOFF);
    int r = tid / 12, lu0 = (tid - r * 12) * 4;
    short4v hv, lv; float4v cn4;
    #pragma unroll
    for (int j = 0; j < 4; ++j) {
      int lu = lu0 + j;
      int u = m * UPM + lu;
      float gi = gb[r * 200 + lu]       + bsum[u];
      float gf = gb[r * 200 + 48 + lu]  + bsum[Hn + u];
      float gg = gb[r * 200 + 96 + lu]  + bsum[2 * Hn + u];
      float go = gb[r * 200 + 144 + lu] + bsum[3 * Hn + u];
      float cn = sigmoid_f(gf) * creg[j] + sigmoid_f(gi) * tanh_f(gg);
      float hn = sigmoid_f(go) * tanh_f(cn);
      cn4[j] = cn;
      unsigned short h = f2bf(hn);
      hv[j] = (short)h;
      lv[j] = (short)f2bf(hn - bf2f(h));
    }
    creg = cn4;
    size_t idx = (size_t)(grow0 + r) * Hn + m * UPM + lu0;
    *(short4v*)(hhi + idx) = hv;
    *(short4v*)(hlo + idx) = lv;
    if (ownh2) {
      int g0 = lu0 >> 3, rem = (lu0 & 7) * 2;
      int off = r * 128 + ((g0 ^ (r & 7)) << 4) + rem;
      *(short4v*)(ownh2 + off) = hv;
      *(short4v*)(ownh2 + 4096 + off) = lv;
    }
  }
}

// P3: l1 partial over member's K-slice (padded to 64) -> zp
__device__ __forceinline__ void p3_do(const MainP& P, const char* smem, int gid, int m,
                                      int wv, int lr, int lk) {
  f32x4 acc[2][4];
  #pragma unroll
  for (int a = 0; a < 2; ++a)
    #pragma unroll
    for (int b = 0; b < 4; ++b) acc[a][b] = (f32x4){0.f,0.f,0.f,0.f};
  const char* ob = smem + OOFF;
  const int rsw = lr & 7;
  #pragma unroll
  for (int kk = 0; kk < 2; ++kk) {
    int kg = kk * 4 + lk;
    int ao = ((kg ^ rsw) << 4);
    bfrag a0h = *(const bfrag*)(ob + lr * 128 + ao);
    bfrag a0l = *(const bfrag*)(ob + 4096 + lr * 128 + ao);
    bfrag a1h = *(const bfrag*)(ob + (16 + lr) * 128 + ao);
    bfrag a1l = *(const bfrag*)(ob + 4096 + (16 + lr) * 128 + ao);
    #pragma unroll
    for (int i = 0; i < 4; ++i) {
      const unsigned short* bp = P.l1wp + (size_t)((wv * 4 + i) * 16 + lr) * 1024 + m * 64 + kk * 32 + lk * 8;
      bfrag bw = *(const bfrag*)bp;
      acc[0][i] = MFMA(a0h, bw, acc[0][i]); acc[0][i] = MFMA(a0l, bw, acc[0][i]);
      acc[1][i] = MFMA(a1h, bw, acc[1][i]); acc[1][i] = MFMA(a1l, bw, acc[1][i]);
    }
  }
  float* zb = P.zp + (size_t)(gid * NMEM + m) * MROWS * 512;
  #pragma unroll
  for (int rfi = 0; rfi < 2; ++rfi)
    #pragma unroll
    for (int i = 0; i < 4; ++i)
      #pragma unroll
      for (int j = 0; j < 4; ++j)
        zb[(rfi * 16 + lk * 4 + j) * 512 + (wv * 4 + i) * 16 + lr] = acc[rfi][i][j];
}

// P4a: sum 16 partials + bias + gen-dot + selu -> a1 (hi/lo)  [cols m*32..m*32+32)]
__device__ __forceinline__ void p4a_do(const MainP& P, int gid, int m, int grow0, int t1, int tid) {
  int r = tid >> 4;
  int cc = m * 32 + (tid & 15) * 2;
  int grow = grow0 + r;
  float s0 = P.l1b[cc], s1 = P.l1b[cc + 1];
  #pragma unroll 4
  for (int mm = 0; mm < NMEM; ++mm) {
    const float* zr = P.zp + ((size_t)(gid * NMEM + mm) * MROWS + r) * 512 + cc;
    float2 v = *(const float2*)zr;
    s0 += v.x; s1 += v.y;
  }
  const float* xg = P.x + ((size_t)t1 * Bn + grow) * XW + Fn;
  const float* w0 = P.l1w_f + (size_t)cc * 780 + 768;
  const float* w1 = w0 + 780;
  #pragma unroll
  for (int qq = 0; qq < Gn; ++qq) {
    float xv = xg[qq];
    s0 += xv * w0[qq];
    s1 += xv * w1[qq];
  }
  float a0 = (s0 > 0.f) ? 1.0507009873554805f * s0 : 1.7580993408473766f * (__expf(s0) - 1.f);
  float a1v = (s1 > 0.f) ? 1.0507009873554805f * s1 : 1.7580993408473766f * (__expf(s1) - 1.f);
  unsigned short h0 = f2bf(a0), h1 = f2bf(a1v);
  size_t ob = (size_t)grow * 512 + cc;
  P.a1hi[ob] = h0;     P.a1hi[ob + 1] = h1;
  P.a1lo[ob] = f2bf(a0 - bf2f(h0));
  P.a1lo[ob + 1] = f2bf(a1v - bf2f(h1));
}

// P4b: stage a1, l2 MFMA (members 0..7, waves 0..1) -> out
__device__ __forceinline__ void p4b_do(const MainP& P, char* smem, int m, int grow0,
                                       int t1, int tid, int wv, int lr, int lk) {
  if (m < 8) {
    #pragma unroll
    for (int it = 0; it < 8; ++it) {
      int idx = tid + it * NT;          // 0..4095
      int hl = idx >> 11;
      int i2 = idx & 2047;
      int r = i2 >> 6, gq = i2 & 63;
      const unsigned short* src = (hl ? P.a1lo : P.a1hi) + (size_t)(grow0 + r) * 512 + gq * 8;
      short8 v = *(const short8*)src;
      *(short8*)(smem + hl * 32768 + r * 1024 + ((gq ^ (r & 7)) << 4)) = v;
    }
    __syncthreads();
    if (wv < 2) {
      f32x4 o = {0.f,0.f,0.f,0.f};
      const unsigned short* bp = P.l2wb + (size_t)(m * 16 + lr) * 512;
      const int rr2 = wv * 16 + lr;
      const int rsw = rr2 & 7;
      const char* ab = smem + rr2 * 1024;
      #pragma unroll 4
      for (int kk = 0; kk < 16; ++kk) {
        int kg = kk * 4 + lk;
        int ao = ((kg ^ rsw) << 4);
        bfrag ah = *(const bfrag*)(ab + ao);
        bfrag al = *(const bfrag*)(ab + 32768 + ao);
        bfrag bw = *(const bfrag*)(bp + kk * 32 + lk * 8);
        o = MFMA(ah, bw, o); o = MFMA(al, bw, o);
      }
      int col = m * 16 + lr;
      float bb = P.l2b[col];
      #pragma unroll
      for (int j = 0; j < 4; ++j) {
        int row = grow0 + wv * 16 + lk * 4 + j;
        P.out[((size_t)t1 * Bn + row) * An + col] = o[j] + bb;
      }
    }
    __syncthreads();
  }
}

__global__ __launch_bounds__(NT) void lstm_main(MainP P) {
  extern __shared__ char smem[];
  const int tid = threadIdx.x;
  const int bid = blockIdx.x;
  const int lane = tid & 63;
  const int wv = tid >> 6;
  const int lr = lane & 15;
  const int lk = lane >> 4;
  const int m = bid & 15;          // member -> XCD m%8 (heuristic)
  const int gid = bid >> 4;        // row group
  const int grow0 = gid * MROWS;
  const int q = wv & 3;            // gate
  const int rf = wv >> 2;          // row frag
  const int rr = rf * 16 + lr;
  const int fbase = gid * NMEM;
  const size_t wr1 = (size_t)(q * Hn + m * UPM + lr);

  float4v c1reg = {0.f,0.f,0.f,0.f}, c2reg = {0.f,0.f,0.f,0.f};

  for (int t = 0; t < Tn; ++t) {
    const int p = t & 1;
    const unsigned short* h1hiP = P.h1 + (size_t)(p * 2)     * HSTR;
    const unsigned short* h1loP = P.h1 + (size_t)(p * 2 + 1) * HSTR;
    unsigned short* h1hiC = P.h1 + (size_t)((p ^ 1) * 2)     * HSTR;
    unsigned short* h1loC = P.h1 + (size_t)((p ^ 1) * 2 + 1) * HSTR;
    const unsigned short* h2hiP = P.h2 + (size_t)(p * 2)     * HSTR;
    const unsigned short* h2loP = P.h2 + (size_t)(p * 2 + 1) * HSTR;
    unsigned short* h2hiC = P.h2 + (size_t)((p ^ 1) * 2)     * HSTR;
    unsigned short* h2loC = P.h2 + (size_t)((p ^ 1) * 2 + 1) * HSTR;

    // ============ PHASE A: gates1 + cell1 (+ deferred P4a(t-1)) ============
    stage_x(P, smem, t, grow0, tid);
    stage_h(smem, h1hiP, h1loP, grow0, 0, tid);
    if (t > 0) p4a_do(P, gid, m, grow0, t - 1, tid);
    __syncthreads();

    f32x4 A0 = {0.f,0.f,0.f,0.f}, A1 = A0, A2 = A0;
    mfma_x4(smem, P.Wih1 + wr1 * 128, rr, lk, A0, A1, A2);
    mfma_h12(smem, P.Whh1 + wr1 * Hn, rr, lk, A0, A1, A2);
    __syncthreads();
    stage_h(smem, h1hiP, h1loP, grow0, 384, tid);
    __syncthreads();
    mfma_h12(smem, P.Whh1 + wr1 * Hn + 384, rr, lk, A0, A1, A2);
    write_gbuf(smem, A0, A1, A2, rf, q, lr, lk);
    __syncthreads();
    if (tid < 384) {
      cell_do(smem, P.b1s, c1reg, h1hiC, h1loC, grow0, m, tid, nullptr);
    } else if (t == 0) {
      // zero own-h2 pad units 48..63 (once)
      int idx = tid - 384;               // 0..127
      int r = idx >> 2, lu0 = 48 + (idx & 3) * 4;
      int g0 = lu0 >> 3, rem = (lu0 & 7) * 2;
      int off = r * 128 + ((g0 ^ (r & 7)) << 4) + rem;
      short4v z = {0,0,0,0};
      *(short4v*)(smem + OOFF + off) = z;
      *(short4v*)(smem + OOFF + 4096 + off) = z;
    }
    group_bar(P.flags, fbase, m, 2 * t + 1);

    // ============ PHASE B: gates2 + cell2 + P3 (+ deferred P4b(t-1)) ============
    if (t > 0) p4b_do(P, smem, m, grow0, t - 1, tid, wv, lr, lk);

    A0 = (f32x4){0.f,0.f,0.f,0.f}; A1 = A0; A2 = A0;
    stage_h(smem, h1hiC, h1loC, grow0, 0, tid);
    __syncthreads();
    mfma_h12(smem, P.Wih2 + wr1 * Hn, rr, lk, A0, A1, A2);
    __syncthreads();
    stage_h(smem, h1hiC, h1loC, grow0, 384, tid);
    __syncthreads();
    mfma_h12(smem, P.Wih2 + wr1 * Hn + 384, rr, lk, A0, A1, A2);
    __syncthreads();
    stage_h(smem, h2hiP, h2loP, grow0, 0, tid);
    __syncthreads();
    mfma_h12(smem, P.Whh2 + wr1 * Hn, rr, lk, A0, A1, A2);
    __syncthreads();
    stage_h(smem, h2hiP, h2loP, grow0, 384, tid);
    __syncthreads();
    mfma_h12(smem, P.Whh2 + wr1 * Hn + 384, rr, lk, A0, A1, A2);
    write_gbuf(smem, A0, A1, A2, rf, q, lr, lk);
    __syncthreads();
    cell_do(smem, P.b2s, c2reg, h2hiC, h2loC, grow0, m, tid, smem + OOFF);
    __syncthreads();
    p3_do(P, smem, gid, m, wv, lr, lk);
    group_bar(P.flags, fbase, m, 2 * t + 2);
  }

  // ============ epilogue: head for t = Tn-1 ============
  p4a_do(P, gid, m, grow0, Tn - 1, tid);
  group_bar(P.flags, fbase, m, 2 * Tn + 1);
  p4b_do(P, smem, m, grow0, Tn - 1, tid, wv, lr, lk);
}

// ---------------- launch ----------------
extern "C" void kernel_launch(void* const* d_in, const int* in_sizes, int n_in,
                              void* d_out, int out_size, void* d_ws, size_t ws_size,
                              hipStream_t stream) {
  const float* x     = (const float*)d_in[0];
  const float* Wih1f = (const float*)d_in[1];
  const float* Whh1f = (const float*)d_in[2];
  const float* bih1  = (const float*)d_in[3];
  const float* bhh1  = (const float*)d_in[4];
  const float* Wih2f = (const float*)d_in[5];
  const float* Whh2f = (const float*)d_in[6];
  const float* bih2  = (const float*)d_in[7];
  const float* bhh2  = (const float*)d_in[8];
  const float* l1wf  = (const float*)d_in[9];
  const float* l1b   = (const float*)d_in[10];
  const float* l2wf  = (const float*)d_in[11];
  const float* l2b   = (const float*)d_in[12];

  char* ws = (char*)d_ws;
  constexpr size_t o_Wih1 = 0;
  constexpr size_t o_Whh1 = o_Wih1 + (size_t)3072 * 128 * 2;
  constexpr size_t o_Wih2 = o_Whh1 + (size_t)3072 * 768 * 2;
  constexpr size_t o_Whh2 = o_Wih2 + (size_t)3072 * 768 * 2;
  constexpr size_t o_l1wp = o_Whh2 + (size_t)3072 * 768 * 2;
  constexpr size_t o_l2wb = o_l1wp + (size_t)512 * 1024 * 2;
  constexpr size_t o_b1s  = o_l2wb + (size_t)128 * 512 * 2;
  constexpr size_t o_b2s  = o_b1s + (size_t)3072 * 4;
  constexpr size_t o_h1   = o_b2s + (size_t)3072 * 4;
  constexpr size_t o_h2   = o_h1 + (size_t)4 * 512 * 768 * 2;
  constexpr size_t o_a1hi = o_h2 + (size_t)4 * 512 * 768 * 2;
  constexpr size_t o_a1lo = o_a1hi + (size_t)512 * 512 * 2;
  constexpr size_t o_zp   = o_a1lo + (size_t)512 * 512 * 2;
  constexpr size_t o_flg  = o_zp + (size_t)16 * 16 * 32 * 512 * 4;

  SetupP sp;
  sp.Wih1f = Wih1f; sp.Whh1f = Whh1f; sp.Wih2f = Wih2f; sp.Whh2f = Whh2f;
  sp.l1wf = l1wf; sp.l2wf = l2wf; sp.bih1 = bih1; sp.bhh1 = bhh1; sp.bih2 = bih2; sp.bhh2 = bhh2;
  sp.Wih1 = (unsigned short*)(ws + o_Wih1);
  sp.Whh1 = (unsigned short*)(ws + o_Whh1);
  sp.Wih2 = (unsigned short*)(ws + o_Wih2);
  sp.Whh2 = (unsigned short*)(ws + o_Whh2);
  sp.l1wp = (unsigned short*)(ws + o_l1wp);
  sp.l2wb = (unsigned short*)(ws + o_l2wb);
  sp.b1s  = (float*)(ws + o_b1s);
  sp.b2s  = (float*)(ws + o_b2s);
  sp.h1   = (unsigned short*)(ws + o_h1);
  sp.h2   = (unsigned short*)(ws + o_h2);
  sp.flags = (int*)(ws + o_flg);
  setup_kernel<<<2048, 256, 0, stream>>>(sp);

  MainP mp;
  mp.x = x; mp.l1w_f = l1wf; mp.l1b = l1b; mp.l2b = l2b;
  mp.Wih1 = sp.Wih1; mp.Whh1 = sp.Whh1; mp.Wih2 = sp.Wih2; mp.Whh2 = sp.Whh2;
  mp.l1wp = sp.l1wp; mp.l2wb = sp.l2wb;
  mp.b1s = sp.b1s; mp.b2s = sp.b2s;
  mp.h1 = sp.h1; mp.h2 = sp.h2;
  mp.a1hi = (unsigned short*)(ws + o_a1hi);
  mp.a1lo = (unsigned short*)(ws + o_a1lo);
  mp.zp   = (float*)(ws + o_zp);
  mp.out  = (float*)d_out;
  mp.flags = sp.flags;

  hipFuncSetAttribute((const void*)lstm_main,
                      hipFuncAttributeMaxDynamicSharedMemorySize, SMEM_BYTES);
  lstm_main<<<NB, NT, SMEM_BYTES, stream>>>(mp);
}

// Round 4
// 52666.541 us; speedup vs baseline: 1.8145x; 1.0876x over previous
//
#include <hip/hip_runtime.h>

#define Tn 512
#define Bn 512
#define Fn 128
#define Gn 12
#define Hn 768
#define XW 140   // F+G
#define D1n 512
#define An 128
#define NT 512
#define NB 256
#define NGRP 16
#define NMEM 16
#define MROWS 32
#define UPM 48

// LDS layout (dynamic, 99328 B)
#define XOFF 0        // x stage: 32 rows x 256B hi, lo at +8192  (16KB)
#define HOFF 16384    // h half-stage: 32 x 768B hi, lo at +24576 (48KB) -> [16384,65536)
#define OOFF 65536    // own-h2: hi 4KB, lo 4KB -> [65536,73728)
#define GOFF 73728    // gbuf fp32 [32][200] = 25600B -> [73728,99328)
#define SMEM_BYTES 99328

using bfrag  = __attribute__((ext_vector_type(8))) short;
using f32x4  = __attribute__((ext_vector_type(4))) float;
using short8 = __attribute__((ext_vector_type(8))) short;
using short4v= __attribute__((ext_vector_type(4))) short;
using float4v= __attribute__((ext_vector_type(4))) float;

static const size_t HSTR = (size_t)Bn * Hn;   // 393216

__device__ __forceinline__ unsigned short f2bf(float x) {
  union { float f; unsigned int u; } v; v.f = x;
  unsigned int r = v.u + 0x7FFFu + ((v.u >> 16) & 1u);
  return (unsigned short)(r >> 16);
}
__device__ __forceinline__ float bf2f(unsigned short h) {
  union { unsigned int u; float f; } v; v.u = ((unsigned int)h) << 16; return v.f;
}
__device__ __forceinline__ float sigmoid_f(float x) { return 1.f / (1.f + __expf(-x)); }
__device__ __forceinline__ float tanh_f(float x) {
  x = fminf(fmaxf(x, -15.f), 15.f);
  float e = __expf(2.f * x);
  return (e - 1.f) / (e + 1.f);
}
__device__ __forceinline__ f32x4 MFMA(bfrag a, bfrag b, f32x4 c) {
  return __builtin_amdgcn_mfma_f32_16x16x32_bf16(a, b, c, 0, 0, 0);
}

// LLC-direct 8B load (sc0 sc1): coherent read, bypasses L1/L2, no invalidate needed.
__device__ __forceinline__ unsigned long long sysload8(const void* p) {
  return __hip_atomic_load((const unsigned long long*)p, __ATOMIC_RELAXED,
                           __HIP_MEMORY_SCOPE_SYSTEM);
}

// ---------------- group barrier: release-only (writeback, NO invalidate) ----------------
__device__ __forceinline__ void group_bar(int* flags, int fbase, int member, int target) {
  __syncthreads();                       // all waves' stores L2-acked
  if (threadIdx.x == 0) {
    // s_waitcnt + buffer_wbl2: push dirty L2 -> LLC. No buffer_inv -> weights stay hot.
    __builtin_amdgcn_fence(__ATOMIC_RELEASE, "agent");
    __hip_atomic_store(flags + (size_t)(fbase + member) * 32, target,
                       __ATOMIC_RELAXED, __HIP_MEMORY_SCOPE_SYSTEM);
  }
  if (threadIdx.x < NMEM) {
    while ((int)__hip_atomic_load(flags + (size_t)(fbase + threadIdx.x) * 32,
                                  __ATOMIC_RELAXED, __HIP_MEMORY_SCOPE_SYSTEM) < target)
      __builtin_amdgcn_s_sleep(1);
  }
  __syncthreads();
}

// ---------------- setup ----------------
struct SetupP {
  const float *Wih1f, *Whh1f, *Wih2f, *Whh2f, *l1wf, *l2wf, *bih1, *bhh1, *bih2, *bhh2;
  unsigned short *Wih1, *Whh1, *Wih2, *Whh2, *l1wp, *l2wb;
  float *b1s, *b2s;
  unsigned short *h1, *h2;
  int* flags;
};

__global__ void setup_kernel(SetupP sp) {
  const size_t gtid = (size_t)blockIdx.x * blockDim.x + threadIdx.x;
  const size_t gs = (size_t)gridDim.x * blockDim.x;
  for (size_t i = gtid; i < 3072u*128u; i += gs) sp.Wih1[i] = f2bf(sp.Wih1f[i]);
  for (size_t i = gtid; i < 3072u*768u; i += gs) sp.Whh1[i] = f2bf(sp.Whh1f[i]);
  for (size_t i = gtid; i < 3072u*768u; i += gs) sp.Wih2[i] = f2bf(sp.Wih2f[i]);
  for (size_t i = gtid; i < 3072u*768u; i += gs) sp.Whh2[i] = f2bf(sp.Whh2f[i]);
  for (size_t i = gtid; i < 512u*1024u; i += gs) {
    size_t c = i >> 10, k = i & 1023, mm = k >> 6, kk = k & 63;
    sp.l1wp[i] = (kk < 48u) ? f2bf(sp.l1wf[c * 780u + mm * 48u + kk]) : (unsigned short)0;
  }
  for (size_t i = gtid; i < 128u*512u; i += gs) sp.l2wb[i] = f2bf(sp.l2wf[i]);
  for (size_t i = gtid; i < 3072u; i += gs) {
    sp.b1s[i] = sp.bih1[i] + sp.bhh1[i];
    sp.b2s[i] = sp.bih2[i] + sp.bhh2[i];
  }
  for (size_t i = gtid; i < 4u*HSTR; i += gs) { sp.h1[i] = 0; sp.h2[i] = 0; }
  for (size_t i = gtid; i < 8192u; i += gs) sp.flags[i] = 0;
}

// ---------------- main ----------------
struct MainP {
  const float* x;
  const float *l1w_f, *l1b, *l2b;
  const unsigned short *Wih1, *Whh1, *Wih2, *Whh2, *l1wp, *l2wb;
  const float *b1s, *b2s;
  unsigned short *h1, *h2, *a1hi, *a1lo;
  float *zp, *out;
  int* flags;
};

__device__ __forceinline__ void stage_x(const MainP& P, char* smem, int t, int grow0, int tid) {
  int r = tid >> 4, c0 = (tid & 15) * 8;
  const float* xp = P.x + ((size_t)t * Bn + grow0 + r) * XW + c0;
  float4v v0 = *(const float4v*)xp;
  float4v v1 = *(const float4v*)(xp + 4);
  short8 hv, lv;
  #pragma unroll
  for (int j = 0; j < 4; ++j) {
    unsigned short h = f2bf(v0[j]); hv[j] = (short)h; lv[j] = (short)f2bf(v0[j] - bf2f(h));
  }
  #pragma unroll
  for (int j = 0; j < 4; ++j) {
    unsigned short h = f2bf(v1[j]); hv[4+j] = (short)h; lv[4+j] = (short)f2bf(v1[j] - bf2f(h));
  }
  int g = tid & 15;
  int off = r * 256 + ((g ^ (r & 7)) << 4);
  *(short8*)(smem + XOFF + off) = hv;
  *(short8*)(smem + XOFF + 8192 + off) = lv;
}

// issue 12 LLC-direct 8B loads (half h-tile: 32 rows x 384 units, hi+lo) into regs
__device__ __forceinline__ void stage_issue(unsigned long long (&R)[12],
    const unsigned short* hsrc_hi, const unsigned short* hsrc_lo,
    int grow0, int koff, int tid) {
  #pragma unroll
  for (int it = 0; it < 12; ++it) {
    int idx = tid + it * NT;             // 0..6143
    int hl = (idx >= 3072) ? 1 : 0;
    int i2 = idx - hl * 3072;
    int r = i2 / 96, gq4 = i2 - r * 96;  // 96 4-unit quads per row
    const unsigned short* src = (hl ? hsrc_lo : hsrc_hi)
        + (size_t)(grow0 + r) * Hn + koff + gq4 * 4;
    R[it] = sysload8(src);
  }
}
__device__ __forceinline__ void stage_commit(const unsigned long long (&R)[12],
    char* smem, int tid) {
  #pragma unroll
  for (int it = 0; it < 12; ++it) {
    int idx = tid + it * NT;
    int hl = (idx >= 3072) ? 1 : 0;
    int i2 = idx - hl * 3072;
    int r = i2 / 96, gq4 = i2 - r * 96;
    int gq = gq4 >> 1;
    *(unsigned long long*)(smem + HOFF + hl * 24576 + r * 768
        + ((gq ^ (r & 7)) << 4) + (gq4 & 1) * 8) = R[it];
  }
}

__device__ __forceinline__ void mfma_x4(const char* smem, const unsigned short* bp, int rr, int lk,
                                        f32x4& A0, f32x4& A1, f32x4& A2) {
  const int rsw = rr & 7;
  const char* ax = smem + XOFF + rr * 256;
  #pragma unroll
  for (int kk = 0; kk < 4; ++kk) {
    int kg = kk * 4 + lk;
    int ao = ((kg ^ rsw) << 4);
    bfrag ahi = *(const bfrag*)(ax + ao);
    bfrag alo = *(const bfrag*)(ax + 8192 + ao);
    bfrag b0 = *(const bfrag*)(bp + kk * 32 + lk * 8);
    bfrag b1 = *(const bfrag*)(bp + 16 * 128 + kk * 32 + lk * 8);
    bfrag b2 = *(const bfrag*)(bp + 32 * 128 + kk * 32 + lk * 8);
    A0 = MFMA(ahi, b0, A0); A0 = MFMA(alo, b0, A0);
    A1 = MFMA(ahi, b1, A1); A1 = MFMA(alo, b1, A1);
    A2 = MFMA(ahi, b2, A2); A2 = MFMA(alo, b2, A2);
  }
}

__device__ __forceinline__ void mfma_h12(const char* smem, const unsigned short* bp, int rr, int lk,
                                         f32x4& A0, f32x4& A1, f32x4& A2) {
  const int rsw = rr & 7;
  const char* ah = smem + HOFF + rr * 768;
  #pragma unroll 4
  for (int kk = 0; kk < 12; ++kk) {
    int kg = kk * 4 + lk;
    int ao = ((kg ^ rsw) << 4);
    bfrag ahi = *(const bfrag*)(ah + ao);
    bfrag alo = *(const bfrag*)(ah + 24576 + ao);
    bfrag b0 = *(const bfrag*)(bp + kk * 32 + lk * 8);
    bfrag b1 = *(const bfrag*)(bp + 16 * 768 + kk * 32 + lk * 8);
    bfrag b2 = *(const bfrag*)(bp + 32 * 768 + kk * 32 + lk * 8);
    A0 = MFMA(ahi, b0, A0); A0 = MFMA(alo, b0, A0);
    A1 = MFMA(ahi, b1, A1); A1 = MFMA(alo, b1, A1);
    A2 = MFMA(ahi, b2, A2); A2 = MFMA(alo, b2, A2);
  }
}

__device__ __forceinline__ void write_gbuf(char* smem, const f32x4& A0, const f32x4& A1,
                                           const f32x4& A2, int rf, int q, int lr, int lk) {
  float* gb = (float*)(smem + GOFF);
  int base = (rf * 16 + lk * 4) * 200 + q * 48 + lr;
  #pragma unroll
  for (int j = 0; j < 4; ++j) {
    gb[base + j * 200]      = A0[j];
    gb[base + j * 200 + 16] = A1[j];
    gb[base + j * 200 + 32] = A2[j];
  }
}

__device__ __forceinline__ void cell_do(const char* smem, const float* bsum,
    float4v& creg, unsigned short* hhi, unsigned short* hlo,
    int grow0, int m, int tid, char* ownh2) {
  if (tid < 384) {
    const float* gb = (const float*)(smem + GOFF);
    int r = tid / 12, lu0 = (tid - r * 12) * 4;
    short4v hv, lv; float4v cn4;
    #pragma unroll
    for (int j = 0; j < 4; ++j) {
      int lu = lu0 + j;
      int u = m * UPM + lu;
      float gi = gb[r * 200 + lu]       + bsum[u];
      float gf = gb[r * 200 + 48 + lu]  + bsum[Hn + u];
      float gg = gb[r * 200 + 96 + lu]  + bsum[2 * Hn + u];
      float go = gb[r * 200 + 144 + lu] + bsum[3 * Hn + u];
      float cn = sigmoid_f(gf) * creg[j] + sigmoid_f(gi) * tanh_f(gg);
      float hn = sigmoid_f(go) * tanh_f(cn);
      cn4[j] = cn;
      unsigned short h = f2bf(hn);
      hv[j] = (short)h;
      lv[j] = (short)f2bf(hn - bf2f(h));
    }
    creg = cn4;
    size_t idx = (size_t)(grow0 + r) * Hn + m * UPM + lu0;
    *(short4v*)(hhi + idx) = hv;
    *(short4v*)(hlo + idx) = lv;
    if (ownh2) {
      int g0 = lu0 >> 3, rem = (lu0 & 7) * 2;
      int off = r * 128 + ((g0 ^ (r & 7)) << 4) + rem;
      *(short4v*)(ownh2 + off) = hv;
      *(short4v*)(ownh2 + 4096 + off) = lv;
    }
  }
}

__device__ __forceinline__ void p3_do(const MainP& P, const char* smem, int gid, int m,
                                      int wv, int lr, int lk) {
  f32x4 acc[2][4];
  #pragma unroll
  for (int a = 0; a < 2; ++a)
    #pragma unroll
    for (int b = 0; b < 4; ++b) acc[a][b] = (f32x4){0.f,0.f,0.f,0.f};
  const char* ob = smem + OOFF;
  const int rsw = lr & 7;
  #pragma unroll
  for (int kk = 0; kk < 2; ++kk) {
    int kg = kk * 4 + lk;
    int ao = ((kg ^ rsw) << 4);
    bfrag a0h = *(const bfrag*)(ob + lr * 128 + ao);
    bfrag a0l = *(const bfrag*)(ob + 4096 + lr * 128 + ao);
    bfrag a1h = *(const bfrag*)(ob + (16 + lr) * 128 + ao);
    bfrag a1l = *(const bfrag*)(ob + 4096 + (16 + lr) * 128 + ao);
    #pragma unroll
    for (int i = 0; i < 4; ++i) {
      const unsigned short* bp = P.l1wp + (size_t)((wv * 4 + i) * 16 + lr) * 1024 + m * 64 + kk * 32 + lk * 8;
      bfrag bw = *(const bfrag*)bp;
      acc[0][i] = MFMA(a0h, bw, acc[0][i]); acc[0][i] = MFMA(a0l, bw, acc[0][i]);
      acc[1][i] = MFMA(a1h, bw, acc[1][i]); acc[1][i] = MFMA(a1l, bw, acc[1][i]);
    }
  }
  float* zb = P.zp + (size_t)(gid * NMEM + m) * MROWS * 512;
  #pragma unroll
  for (int rfi = 0; rfi < 2; ++rfi)
    #pragma unroll
    for (int i = 0; i < 4; ++i)
      #pragma unroll
      for (int j = 0; j < 4; ++j)
        zb[(rfi * 16 + lk * 4 + j) * 512 + (wv * 4 + i) * 16 + lr] = acc[rfi][i][j];
}

// P4a: sum 16 zp partials (LLC-direct) + bias + gen-dot + selu -> a1
__device__ __forceinline__ void p4a_do(const MainP& P, int gid, int m, int grow0, int t1, int tid) {
  int r = tid >> 4;
  int cc = m * 32 + (tid & 15) * 2;
  int grow = grow0 + r;
  float s0 = P.l1b[cc], s1 = P.l1b[cc + 1];
  #pragma unroll 4
  for (int mm = 0; mm < NMEM; ++mm) {
    const float* zr = P.zp + ((size_t)(gid * NMEM + mm) * MROWS + r) * 512 + cc;
    union { unsigned long long u; float f[2]; } cv;
    cv.u = sysload8(zr);
    s0 += cv.f[0]; s1 += cv.f[1];
  }
  const float* xg = P.x + ((size_t)t1 * Bn + grow) * XW + Fn;
  const float* w0 = P.l1w_f + (size_t)cc * 780 + 768;
  const float* w1 = w0 + 780;
  #pragma unroll
  for (int qq = 0; qq < Gn; ++qq) {
    float xv = xg[qq];
    s0 += xv * w0[qq];
    s1 += xv * w1[qq];
  }
  float a0 = (s0 > 0.f) ? 1.0507009873554805f * s0 : 1.7580993408473766f * (__expf(s0) - 1.f);
  float a1v = (s1 > 0.f) ? 1.0507009873554805f * s1 : 1.7580993408473766f * (__expf(s1) - 1.f);
  unsigned short h0 = f2bf(a0), h1 = f2bf(a1v);
  size_t ob = (size_t)grow * 512 + cc;
  P.a1hi[ob] = h0;     P.a1hi[ob + 1] = h1;
  P.a1lo[ob] = f2bf(a0 - bf2f(h0));
  P.a1lo[ob + 1] = f2bf(a1v - bf2f(h1));
}

// P4b: stage a1 (LLC-direct), l2 MFMA (members 0..7) -> out
__device__ __forceinline__ void p4b_do(const MainP& P, char* smem, int m, int grow0,
                                       int t1, int tid, int wv, int lr, int lk) {
  if (m < 8) {
    #pragma unroll
    for (int it = 0; it < 16; ++it) {
      int idx = tid + it * NT;          // 0..8191
      int hl = idx >> 12;
      int i2 = idx & 4095;
      int r = i2 >> 7, gq4 = i2 & 127;
      const unsigned short* src = (hl ? P.a1lo : P.a1hi) + (size_t)(grow0 + r) * 512 + gq4 * 4;
      unsigned long long v = sysload8(src);
      int gq = gq4 >> 1;
      *(unsigned long long*)(smem + hl * 32768 + r * 1024
          + ((gq ^ (r & 7)) << 4) + (gq4 & 1) * 8) = v;
    }
    __syncthreads();
    if (wv < 2) {
      f32x4 o = {0.f,0.f,0.f,0.f};
      const unsigned short* bp = P.l2wb + (size_t)(m * 16 + lr) * 512;
      const int rr2 = wv * 16 + lr;
      const int rsw = rr2 & 7;
      const char* ab = smem + rr2 * 1024;
      #pragma unroll 4
      for (int kk = 0; kk < 16; ++kk) {
        int kg = kk * 4 + lk;
        int ao = ((kg ^ rsw) << 4);
        bfrag ah = *(const bfrag*)(ab + ao);
        bfrag al = *(const bfrag*)(ab + 32768 + ao);
        bfrag bw = *(const bfrag*)(bp + kk * 32 + lk * 8);
        o = MFMA(ah, bw, o); o = MFMA(al, bw, o);
      }
      int col = m * 16 + lr;
      float bb = P.l2b[col];
      #pragma unroll
      for (int j = 0; j < 4; ++j) {
        int row = grow0 + wv * 16 + lk * 4 + j;
        P.out[((size_t)t1 * Bn + row) * An + col] = o[j] + bb;
      }
    }
    __syncthreads();
  }
}

__global__ __launch_bounds__(NT) void lstm_main(MainP P) {
  extern __shared__ char smem[];
  const int tid = threadIdx.x;
  const int bid = blockIdx.x;
  const int lane = tid & 63;
  const int wv = tid >> 6;
  const int lr = lane & 15;
  const int lk = lane >> 4;
  const int m = bid & 15;
  const int gid = bid >> 4;
  const int grow0 = gid * MROWS;
  const int q = wv & 3;
  const int rf = wv >> 2;
  const int rr = rf * 16 + lr;
  const int fbase = gid * NMEM;
  const size_t wr1 = (size_t)(q * Hn + m * UPM + lr);

  float4v c1reg = {0.f,0.f,0.f,0.f}, c2reg = {0.f,0.f,0.f,0.f};
  unsigned long long R[12];

  for (int t = 0; t < Tn; ++t) {
    const int p = t & 1;
    const unsigned short* h1hiP = P.h1 + (size_t)(p * 2)     * HSTR;
    const unsigned short* h1loP = P.h1 + (size_t)(p * 2 + 1) * HSTR;
    unsigned short* h1hiC = P.h1 + (size_t)((p ^ 1) * 2)     * HSTR;
    unsigned short* h1loC = P.h1 + (size_t)((p ^ 1) * 2 + 1) * HSTR;
    const unsigned short* h2hiP = P.h2 + (size_t)(p * 2)     * HSTR;
    const unsigned short* h2loP = P.h2 + (size_t)(p * 2 + 1) * HSTR;
    unsigned short* h2hiC = P.h2 + (size_t)((p ^ 1) * 2)     * HSTR;
    unsigned short* h2loC = P.h2 + (size_t)((p ^ 1) * 2 + 1) * HSTR;

    // ============ PHASE A: gates1 + cell1 (+ deferred P4a(t-1)) ============
    stage_issue(R, h1hiP, h1loP, grow0, 0, tid);     // LLC loads fly under stage_x/p4a
    stage_x(P, smem, t, grow0, tid);
    if (t > 0) p4a_do(P, gid, m, grow0, t - 1, tid);
    __syncthreads();
    stage_commit(R, smem, tid);
    __syncthreads();

    f32x4 A0 = {0.f,0.f,0.f,0.f}, A1 = A0, A2 = A0;
    stage_issue(R, h1hiP, h1loP, grow0, 384, tid);   // issue half1 under MFMA
    mfma_x4(smem, P.Wih1 + wr1 * 128, rr, lk, A0, A1, A2);
    mfma_h12(smem, P.Whh1 + wr1 * Hn, rr, lk, A0, A1, A2);
    __syncthreads();
    stage_commit(R, smem, tid);
    __syncthreads();
    mfma_h12(smem, P.Whh1 + wr1 * Hn + 384, rr, lk, A0, A1, A2);
    write_gbuf(smem, A0, A1, A2, rf, q, lr, lk);
    __syncthreads();
    if (tid < 384) {
      cell_do(smem, P.b1s, c1reg, h1hiC, h1loC, grow0, m, tid, nullptr);
    } else if (t == 0) {
      int idx = tid - 384;
      int r = idx >> 2, lu0 = 48 + (idx & 3) * 4;
      int g0 = lu0 >> 3, rem = (lu0 & 7) * 2;
      int off = r * 128 + ((g0 ^ (r & 7)) << 4) + rem;
      short4v z = {0,0,0,0};
      *(short4v*)(smem + OOFF + off) = z;
      *(short4v*)(smem + OOFF + 4096 + off) = z;
    }
    group_bar(P.flags, fbase, m, 2 * t + 1);

    // ============ PHASE B: gates2 + cell2 + P3 (+ deferred P4b(t-1)) ============
    stage_issue(R, h1hiC, h1loC, grow0, 0, tid);     // fly under p4b
    if (t > 0) p4b_do(P, smem, m, grow0, t - 1, tid, wv, lr, lk);
    stage_commit(R, smem, tid);
    __syncthreads();

    A0 = (f32x4){0.f,0.f,0.f,0.f}; A1 = A0; A2 = A0;
    stage_issue(R, h1hiC, h1loC, grow0, 384, tid);
    mfma_h12(smem, P.Wih2 + wr1 * Hn, rr, lk, A0, A1, A2);
    __syncthreads();
    stage_commit(R, smem, tid);
    __syncthreads();
    stage_issue(R, h2hiP, h2loP, grow0, 0, tid);
    mfma_h12(smem, P.Wih2 + wr1 * Hn + 384, rr, lk, A0, A1, A2);
    __syncthreads();
    stage_commit(R, smem, tid);
    __syncthreads();
    stage_issue(R, h2hiP, h2loP, grow0, 384, tid);
    mfma_h12(smem, P.Whh2 + wr1 * Hn, rr, lk, A0, A1, A2);
    __syncthreads();
    stage_commit(R, smem, tid);
    __syncthreads();
    mfma_h12(smem, P.Whh2 + wr1 * Hn + 384, rr, lk, A0, A1, A2);
    write_gbuf(smem, A0, A1, A2, rf, q, lr, lk);
    __syncthreads();
    cell_do(smem, P.b2s, c2reg, h2hiC, h2loC, grow0, m, tid, smem + OOFF);
    __syncthreads();
    p3_do(P, smem, gid, m, wv, lr, lk);
    group_bar(P.flags, fbase, m, 2 * t + 2);
  }

  // ============ epilogue: head for t = Tn-1 ============
  p4a_do(P, gid, m, grow0, Tn - 1, tid);
  group_bar(P.flags, fbase, m, 2 * Tn + 1);
  p4b_do(P, smem, m, grow0, Tn - 1, tid, wv, lr, lk);
}

// ---------------- launch ----------------
extern "C" void kernel_launch(void* const* d_in, const int* in_sizes, int n_in,
                              void* d_out, int out_size, void* d_ws, size_t ws_size,
                              hipStream_t stream) {
  const float* x     = (const float*)d_in[0];
  const float* Wih1f = (const float*)d_in[1];
  const float* Whh1f = (const float*)d_in[2];
  const float* bih1  = (const float*)d_in[3];
  const float* bhh1  = (const float*)d_in[4];
  const float* Wih2f = (const float*)d_in[5];
  const float* Whh2f = (const float*)d_in[6];
  const float* bih2  = (const float*)d_in[7];
  const float* bhh2  = (const float*)d_in[8];
  const float* l1wf  = (const float*)d_in[9];
  const float* l1b   = (const float*)d_in[10];
  const float* l2wf  = (const float*)d_in[11];
  const float* l2b   = (const float*)d_in[12];

  char* ws = (char*)d_ws;
  constexpr size_t o_Wih1 = 0;
  constexpr size_t o_Whh1 = o_Wih1 + (size_t)3072 * 128 * 2;
  constexpr size_t o_Wih2 = o_Whh1 + (size_t)3072 * 768 * 2;
  constexpr size_t o_Whh2 = o_Wih2 + (size_t)3072 * 768 * 2;
  constexpr size_t o_l1wp = o_Whh2 + (size_t)3072 * 768 * 2;
  constexpr size_t o_l2wb = o_l1wp + (size_t)512 * 1024 * 2;
  constexpr size_t o_b1s  = o_l2wb + (size_t)128 * 512 * 2;
  constexpr size_t o_b2s  = o_b1s + (size_t)3072 * 4;
  constexpr size_t o_h1   = o_b2s + (size_t)3072 * 4;
  constexpr size_t o_h2   = o_h1 + (size_t)4 * 512 * 768 * 2;
  constexpr size_t o_a1hi = o_h2 + (size_t)4 * 512 * 768 * 2;
  constexpr size_t o_a1lo = o_a1hi + (size_t)512 * 512 * 2;
  constexpr size_t o_zp   = o_a1lo + (size_t)512 * 512 * 2;
  constexpr size_t o_flg  = o_zp + (size_t)16 * 16 * 32 * 512 * 4;

  SetupP sp;
  sp.Wih1f = Wih1f; sp.Whh1f = Whh1f; sp.Wih2f = Wih2f; sp.Whh2f = Whh2f;
  sp.l1wf = l1wf; sp.l2wf = l2wf; sp.bih1 = bih1; sp.bhh1 = bhh1; sp.bih2 = bih2; sp.bhh2 = bhh2;
  sp.Wih1 = (unsigned short*)(ws + o_Wih1);
  sp.Whh1 = (unsigned short*)(ws + o_Whh1);
  sp.Wih2 = (unsigned short*)(ws + o_Wih2);
  sp.Whh2 = (unsigned short*)(ws + o_Whh2);
  sp.l1wp = (unsigned short*)(ws + o_l1wp);
  sp.l2wb = (unsigned short*)(ws + o_l2wb);
  sp.b1s  = (float*)(ws + o_b1s);
  sp.b2s  = (float*)(ws + o_b2s);
  sp.h1   = (unsigned short*)(ws + o_h1);
  sp.h2   = (unsigned short*)(ws + o_h2);
  sp.flags = (int*)(ws + o_flg);
  setup_kernel<<<2048, 256, 0, stream>>>(sp);

  MainP mp;
  mp.x = x; mp.l1w_f = l1wf; mp.l1b = l1b; mp.l2b = l2b;
  mp.Wih1 = sp.Wih1; mp.Whh1 = sp.Whh1; mp.Wih2 = sp.Wih2; mp.Whh2 = sp.Whh2;
  mp.l1wp = sp.l1wp; mp.l2wb = sp.l2wb;
  mp.b1s = sp.b1s; mp.b2s = sp.b2s;
  mp.h1 = sp.h1; mp.h2 = sp.h2;
  mp.a1hi = (unsigned short*)(ws + o_a1hi);
  mp.a1lo = (unsigned short*)(ws + o_a1lo);
  mp.zp   = (float*)(ws + o_zp);
  mp.out  = (float*)d_out;
  mp.flags = sp.flags;

  hipFuncSetAttribute((const void*)lstm_main,
                      hipFuncAttributeMaxDynamicSharedMemorySize, SMEM_BYTES);
  lstm_main<<<NB, NT, SMEM_BYTES, stream>>>(mp);
}

// Round 6
// 37229.865 us; speedup vs baseline: 2.5669x; 1.4146x over previous
//
#include <hip/hip_runtime.h>

#define Tn 512
#define Bn 512
#define Fn 128
#define Gn 12
#define Hn 768
#define XW 140
#define D1n 512
#define An 128
#define NT 512
#define NB 256
#define NMEM 16
#define MROWS 32
#define UPM 48

// LDS layout (dynamic, 155648 B)
#define XOFF 0          // x: 32 r x 256B hi + lo at +8192       [0, 16384)
#define HOFF 16384      // h tile 32 x 1536B hi; lo at +49152    [16384, 114688)
#define LBOFF 114688    // l1 partials [2][32][32] f32 = 8KB     [114688, 122880)
#define AGOFF 122880    // gbuf 32x200 f32 (25600B) OR a1 tile 32x1024B (32768B)
#define SMEM_BYTES 155648

using bfrag  = __attribute__((ext_vector_type(8))) short;
using f32x4  = __attribute__((ext_vector_type(4))) float;
using short8 = __attribute__((ext_vector_type(8))) short;
using short4v= __attribute__((ext_vector_type(4))) short;
using float4v= __attribute__((ext_vector_type(4))) float;

static const size_t HSTR = (size_t)Bn * Hn;

__device__ __forceinline__ unsigned short f2bf(float x) {
  union { float f; unsigned int u; } v; v.f = x;
  unsigned int r = v.u + 0x7FFFu + ((v.u >> 16) & 1u);
  return (unsigned short)(r >> 16);
}
__device__ __forceinline__ float bf2f(unsigned short h) {
  union { unsigned int u; float f; } v; v.u = ((unsigned int)h) << 16; return v.f;
}
__device__ __forceinline__ float sigmoid_f(float x) { return 1.f / (1.f + __expf(-x)); }
__device__ __forceinline__ float tanh_f(float x) {
  x = fminf(fmaxf(x, -15.f), 15.f);
  float e = __expf(2.f * x);
  return (e - 1.f) / (e + 1.f);
}
__device__ __forceinline__ f32x4 MFMA(bfrag a, bfrag b, f32x4 c) {
  return __builtin_amdgcn_mfma_f32_16x16x32_bf16(a, b, c, 0, 0, 0);
}

// LLC-direct 16B load (sc0 sc1 bypasses L1+L2 -> coherent, no invalidate needed)
__device__ __forceinline__ void ld16llc(uint4& d, const void* p) {
  asm volatile("global_load_dwordx4 %0, %1, off sc0 sc1" : "=&v"(d) : "v"(p));
}
__device__ __forceinline__ void vmwait0() {
  asm volatile("s_waitcnt vmcnt(0)" ::: "memory");
  __builtin_amdgcn_sched_barrier(0);
}

// ---- group barrier: R4-proven (release wbl2 fence, system store, system polls) ----
__device__ __forceinline__ void group_bar(int* flags, int fbase, int member, int target) {
  __syncthreads();
  if (threadIdx.x == 0) {
    __builtin_amdgcn_fence(__ATOMIC_RELEASE, "agent");   // s_waitcnt + buffer_wbl2 (no inv)
    __hip_atomic_store(flags + (size_t)(fbase + member) * 32, target,
                       __ATOMIC_RELAXED, __HIP_MEMORY_SCOPE_SYSTEM);
  }
  if (threadIdx.x < NMEM) {
    while (__hip_atomic_load(flags + (size_t)(fbase + threadIdx.x) * 32,
                             __ATOMIC_RELAXED, __HIP_MEMORY_SCOPE_SYSTEM) < target)
      __builtin_amdgcn_s_sleep(1);
  }
  __syncthreads();
}

// ---------------- setup ----------------
struct SetupP {
  const float *Wih1f, *Whh1f, *Wih2f, *Whh2f, *l1wf, *l2wf, *bih1, *bhh1, *bih2, *bhh2;
  unsigned short *Wih1, *Whh1, *Wih2, *Whh2, *l1wb, *l2wb;
  float *b1s, *b2s;
  unsigned short *h1, *h2;
  int* flags;
};

__global__ void setup_kernel(SetupP sp) {
  const size_t gtid = (size_t)blockIdx.x * blockDim.x + threadIdx.x;
  const size_t gs = (size_t)gridDim.x * blockDim.x;
  for (size_t i = gtid; i < 3072u*128u; i += gs) sp.Wih1[i] = f2bf(sp.Wih1f[i]);
  for (size_t i = gtid; i < 3072u*768u; i += gs) sp.Whh1[i] = f2bf(sp.Whh1f[i]);
  for (size_t i = gtid; i < 3072u*768u; i += gs) sp.Wih2[i] = f2bf(sp.Wih2f[i]);
  for (size_t i = gtid; i < 3072u*768u; i += gs) sp.Whh2[i] = f2bf(sp.Whh2f[i]);
  for (size_t i = gtid; i < 512u*768u; i += gs) {
    size_t c = i / 768u, k = i - c * 768u;
    sp.l1wb[i] = f2bf(sp.l1wf[c * 780u + k]);
  }
  for (size_t i = gtid; i < 128u*512u; i += gs) sp.l2wb[i] = f2bf(sp.l2wf[i]);
  for (size_t i = gtid; i < 3072u; i += gs) {
    sp.b1s[i] = sp.bih1[i] + sp.bhh1[i];
    sp.b2s[i] = sp.bih2[i] + sp.bhh2[i];
  }
  for (size_t i = gtid; i < 4u*HSTR; i += gs) { sp.h1[i] = 0; sp.h2[i] = 0; }
  for (size_t i = gtid; i < 8192u; i += gs) sp.flags[i] = 0;
}

// ---------------- main ----------------
struct MainP {
  const float* x;
  const float *l1w_f, *l1b, *l2b;
  const unsigned short *Wih1, *Whh1, *Wih2, *Whh2, *l1wb, *l2wb;
  const float *b1s, *b2s;
  unsigned short *h1, *h2, *a1hi;
  float *out;
  int* flags;
};

__device__ __forceinline__ void stage_x(const MainP& P, char* smem, int t, int grow0, int tid) {
  int r = tid >> 4, c0 = (tid & 15) * 8;
  const float* xp = P.x + ((size_t)t * Bn + grow0 + r) * XW + c0;
  float4v v0 = *(const float4v*)xp;
  float4v v1 = *(const float4v*)(xp + 4);
  short8 hv, lv;
  #pragma unroll
  for (int j = 0; j < 4; ++j) {
    unsigned short h = f2bf(v0[j]); hv[j] = (short)h; lv[j] = (short)f2bf(v0[j] - bf2f(h));
  }
  #pragma unroll
  for (int j = 0; j < 4; ++j) {
    unsigned short h = f2bf(v1[j]); hv[4+j] = (short)h; lv[4+j] = (short)f2bf(v1[j] - bf2f(h));
  }
  int g = tid & 15;
  int off = r * 256 + ((g ^ (r & 7)) << 4);
  *(short8*)(smem + XOFF + off) = hv;
  *(short8*)(smem + XOFF + 8192 + off) = lv;
}

// full 32 x 768 hi/lo tile: 12 x 16B per thread (6144 requests)
__device__ __forceinline__ void h_issue(uint4 (&R)[12], const unsigned short* hi,
    const unsigned short* lo, int grow0, int tid) {
  #pragma unroll
  for (int it = 0; it < 12; ++it) {
    int idx = tid + it * NT;           // 0..6143
    int hl = (idx >= 3072) ? 1 : 0;
    int i2 = idx - hl * 3072;
    int r = i2 / 96, gq = i2 - r * 96; // 96 8-unit granules per row
    ld16llc(R[it], (hl ? lo : hi) + (size_t)(grow0 + r) * Hn + gq * 8);
  }
}
__device__ __forceinline__ void h_commit(uint4 (&R)[12], char* smem, int tid) {
  #pragma unroll
  for (int it = 0; it < 12; ++it) {
    int idx = tid + it * NT;
    int hl = (idx >= 3072) ? 1 : 0;
    int i2 = idx - hl * 3072;
    int r = i2 / 96, gq = i2 - r * 96;
    *(uint4*)(smem + HOFF + hl * 49152 + r * 1536 + ((gq ^ (r & 7)) << 4)) = R[it];
  }
}

// a1 tile (hi only): 32 x 512 = 32KB, 4 x 16B per thread
__device__ __forceinline__ void a1_issue(uint4 (&S)[4], const MainP& P, int grow0, int tid) {
  #pragma unroll
  for (int it = 0; it < 4; ++it) {
    int idx = tid + it * NT;
    int r = idx >> 6, gq = idx & 63;
    ld16llc(S[it], P.a1hi + (size_t)(grow0 + r) * D1n + gq * 8);
  }
}
__device__ __forceinline__ void a1_commit(uint4 (&S)[4], char* smem, int tid) {
  #pragma unroll
  for (int it = 0; it < 4; ++it) {
    int idx = tid + it * NT;
    int r = idx >> 6, gq = idx & 63;
    *(uint4*)(smem + AGOFF + r * 1024 + ((gq ^ (r & 7)) << 4)) = S[it];
  }
}

__device__ __forceinline__ void mfma_x4(const char* smem, const unsigned short* bp, int rr, int lk,
                                        f32x4& A0, f32x4& A1, f32x4& A2) {
  const int rsw = rr & 7;
  const char* ax = smem + XOFF + rr * 256;
  #pragma unroll
  for (int kk = 0; kk < 4; ++kk) {
    int kg = kk * 4 + lk;
    int ao = ((kg ^ rsw) << 4);
    bfrag ahi = *(const bfrag*)(ax + ao);
    bfrag alo = *(const bfrag*)(ax + 8192 + ao);
    bfrag b0 = *(const bfrag*)(bp + kk * 32 + lk * 8);
    bfrag b1 = *(const bfrag*)(bp + 16 * Fn + kk * 32 + lk * 8);
    bfrag b2 = *(const bfrag*)(bp + 32 * Fn + kk * 32 + lk * 8);
    A0 = MFMA(ahi, b0, A0); A0 = MFMA(alo, b0, A0);
    A1 = MFMA(ahi, b1, A1); A1 = MFMA(alo, b1, A1);
    A2 = MFMA(ahi, b2, A2); A2 = MFMA(alo, b2, A2);
  }
}

__device__ __forceinline__ void mfma_h24(const char* smem, const unsigned short* bp, int rr, int lk,
                                         f32x4& A0, f32x4& A1, f32x4& A2) {
  const int rsw = rr & 7;
  const char* ah = smem + HOFF + rr * 1536;
  #pragma unroll 6
  for (int kk = 0; kk < 24; ++kk) {
    int kg = kk * 4 + lk;
    int ao = ((kg ^ rsw) << 4);
    bfrag ahi = *(const bfrag*)(ah + ao);
    bfrag alo = *(const bfrag*)(ah + 49152 + ao);
    bfrag b0 = *(const bfrag*)(bp + kk * 32 + lk * 8);
    bfrag b1 = *(const bfrag*)(bp + 16 * Hn + kk * 32 + lk * 8);
    bfrag b2 = *(const bfrag*)(bp + 32 * Hn + kk * 32 + lk * 8);
    A0 = MFMA(ahi, b0, A0); A0 = MFMA(alo, b0, A0);
    A1 = MFMA(ahi, b1, A1); A1 = MFMA(alo, b1, A1);
    A2 = MFMA(ahi, b2, A2); A2 = MFMA(alo, b2, A2);
  }
}

// l1 partial: wave (nt,mt,kh); member's 32 cols, K=768 split in 2 halves
__device__ __forceinline__ void l1_mfma(const MainP& P, char* smem, int m,
                                        int wv, int lr, int lk) {
  int nt = wv & 1, mt = (wv >> 1) & 1, kh = wv >> 2;
  f32x4 acc = {0.f,0.f,0.f,0.f};
  const int rr = mt * 16 + lr;
  const int rsw = rr & 7;
  const char* ah = smem + HOFF + rr * 1536;
  const unsigned short* bp = P.l1wb + (size_t)(m * 32 + nt * 16 + lr) * Hn + kh * 384;
  #pragma unroll 4
  for (int kk = 0; kk < 12; ++kk) {
    int kg = (kh * 12 + kk) * 4 + lk;
    int ao = ((kg ^ rsw) << 4);
    bfrag ahi = *(const bfrag*)(ah + ao);
    bfrag alo = *(const bfrag*)(ah + 49152 + ao);
    bfrag bw = *(const bfrag*)(bp + kk * 32 + lk * 8);
    acc = MFMA(ahi, bw, acc); acc = MFMA(alo, bw, acc);
  }
  float* lb = (float*)(smem + LBOFF);
  #pragma unroll
  for (int j = 0; j < 4; ++j)
    lb[(kh * 32 + mt * 16 + lk * 4 + j) * 32 + nt * 16 + lr] = acc[j];
}

// l1 finalize: sum K-halves + bias + gen-dot + selu -> a1hi(t1)
__device__ __forceinline__ void l1_final(const MainP& P, const char* smem, int m,
                                         int grow0, int t1, int tid) {
  if (tid < 256) {
    int r = tid >> 3, cq = tid & 7;
    int cc = m * 32 + cq * 4;
    const float* lb = (const float*)(smem + LBOFF);
    const float* xg = P.x + ((size_t)t1 * Bn + grow0 + r) * XW + Fn;
    float xgv[Gn];
    #pragma unroll
    for (int qq = 0; qq < Gn; ++qq) xgv[qq] = xg[qq];
    short4v hv;
    #pragma unroll
    for (int j = 0; j < 4; ++j) {
      int c = cq * 4 + j;
      float s = lb[r * 32 + c] + lb[1024 + r * 32 + c] + P.l1b[cc + j];
      const float* wg = P.l1w_f + (size_t)(cc + j) * 780 + 768;
      #pragma unroll
      for (int qq = 0; qq < Gn; ++qq) s += xgv[qq] * wg[qq];
      float a = (s > 0.f) ? 1.0507009873554805f * s
                          : 1.7580993408473766f * (__expf(s) - 1.f);
      hv[j] = (short)f2bf(a);
    }
    *(short4v*)(P.a1hi + (size_t)(grow0 + r) * D1n + cc) = hv;
  }
}

__device__ __forceinline__ void write_gbuf(char* smem, const f32x4& A0, const f32x4& A1,
                                           const f32x4& A2, int rf, int q, int lr, int lk) {
  float* gb = (float*)(smem + AGOFF);
  int base = (rf * 16 + lk * 4) * 200 + q * 48 + lr;
  #pragma unroll
  for (int j = 0; j < 4; ++j) {
    gb[base + j * 200]      = A0[j];
    gb[base + j * 200 + 16] = A1[j];
    gb[base + j * 200 + 32] = A2[j];
  }
}

__device__ __forceinline__ void cell_do(const char* smem, const float* bsum,
    float4v& creg, unsigned short* hhi, unsigned short* hlo,
    int grow0, int m, int tid) {
  if (tid < 384) {
    const float* gb = (const float*)(smem + AGOFF);
    int r = tid / 12, lu0 = (tid - r * 12) * 4;
    short4v hv, lv; float4v cn4;
    #pragma unroll
    for (int j = 0; j < 4; ++j) {
      int lu = lu0 + j;
      int u = m * UPM + lu;
      float gi = gb[r * 200 + lu]       + bsum[u];
      float gf = gb[r * 200 + 48 + lu]  + bsum[Hn + u];
      float gg = gb[r * 200 + 96 + lu]  + bsum[2 * Hn + u];
      float go = gb[r * 200 + 144 + lu] + bsum[3 * Hn + u];
      float cn = sigmoid_f(gf) * creg[j] + sigmoid_f(gi) * tanh_f(gg);
      float hn = sigmoid_f(go) * tanh_f(cn);
      cn4[j] = cn;
      unsigned short h = f2bf(hn);
      hv[j] = (short)h;
      lv[j] = (short)f2bf(hn - bf2f(h));
    }
    creg = cn4;
    size_t idx = (size_t)(grow0 + r) * Hn + m * UPM + lu0;
    *(short4v*)(hhi + idx) = hv;
    *(short4v*)(hlo + idx) = lv;
  }
}

// l2: members 0..7, waves 0..1, K=512, a1 hi-only -> out(t1)
__device__ __forceinline__ void p4b_mfma(const MainP& P, const char* smem, int m, int grow0,
                                         int t1, int wv, int lr, int lk) {
  if (m < 8 && wv < 2) {
    f32x4 o = {0.f,0.f,0.f,0.f};
    const unsigned short* bp = P.l2wb + (size_t)(m * 16 + lr) * 512;
    const int rr2 = wv * 16 + lr, rsw = rr2 & 7;
    const char* ab = smem + AGOFF + rr2 * 1024;
    #pragma unroll 4
    for (int kk = 0; kk < 16; ++kk) {
      int kg = kk * 4 + lk;
      bfrag ah = *(const bfrag*)(ab + ((kg ^ rsw) << 4));
      bfrag bw = *(const bfrag*)(bp + kk * 32 + lk * 8);
      o = MFMA(ah, bw, o);
    }
    float bb = P.l2b[m * 16 + lr];
    #pragma unroll
    for (int j = 0; j < 4; ++j)
      P.out[((size_t)t1 * Bn + grow0 + wv * 16 + lk * 4 + j) * An + m * 16 + lr] = o[j] + bb;
  }
}

__global__ __launch_bounds__(NT) void lstm_main(MainP P) {
  extern __shared__ char smem[];
  const int tid = threadIdx.x;
  const int bid = blockIdx.x;
  const int lane = tid & 63;
  const int wv = tid >> 6;
  const int lr = lane & 15;
  const int lk = lane >> 4;
  const int m = bid & 15;
  const int gid = bid >> 4;
  const int grow0 = gid * MROWS;
  const int q = wv & 3, rf = wv >> 2;
  const int rr = rf * 16 + lr;
  const int fbase = gid * NMEM;
  const size_t wr1 = (size_t)(q * Hn + m * UPM + lr);

  float4v c1reg = {0.f,0.f,0.f,0.f}, c2reg = {0.f,0.f,0.f,0.f};

  // h1(-1) = 0 in the persistent LDS h tile
  for (int i = tid; i < 24576; i += NT) ((int*)(smem + HOFF))[i] = 0;
  __syncthreads();

  for (int t = 0; t < Tn; ++t) {
    const int p = t & 1;
    unsigned short* h1hiC = P.h1 + (size_t)((p ^ 1) * 2)     * HSTR;
    unsigned short* h1loC = P.h1 + (size_t)((p ^ 1) * 2 + 1) * HSTR;
    const unsigned short* h2hiP = P.h2 + (size_t)(p * 2)     * HSTR;
    const unsigned short* h2loP = P.h2 + (size_t)(p * 2 + 1) * HSTR;
    unsigned short* h2hiC = P.h2 + (size_t)((p ^ 1) * 2)     * HSTR;
    unsigned short* h2loC = P.h2 + (size_t)((p ^ 1) * 2 + 1) * HSTR;

    // ===== PHASE A: [l2 -> out(t-2)] + gates1 + cell1. HOFF holds h1(t-1). =====
    const bool doP4 = (t >= 2) && (m < 8);
    {
      uint4 S[4];
      if (doP4) a1_issue(S, P, grow0, tid);
      stage_x(P, smem, t, grow0, tid);
      __syncthreads();                         // x staged; prev-phase AGOFF reads done
      if (doP4) { vmwait0(); a1_commit(S, smem, tid); }
    }
    __syncthreads();                           // a1 staged
    if (t >= 2) p4b_mfma(P, smem, m, grow0, t - 2, wv, lr, lk);
    {
      f32x4 A0 = {0.f,0.f,0.f,0.f}, A1 = A0, A2 = A0;
      mfma_x4(smem, P.Wih1 + wr1 * Fn, rr, lk, A0, A1, A2);
      mfma_h24(smem, P.Whh1 + wr1 * Hn, rr, lk, A0, A1, A2);
      __syncthreads();                         // p4b a1-reads + MFMA reads done
      write_gbuf(smem, A0, A1, A2, rf, q, lr, lk);
    }
    __syncthreads();
    cell_do(smem, P.b1s, c1reg, h1hiC, h1loC, grow0, m, tid);
    group_bar(P.flags, fbase, m, 2 * t + 1);

    // ===== PHASE B: gates2 + cell2 + l1(t-1). =====
    {
      uint4 R[12];
      h_issue(R, h2hiP, h2loP, grow0, tid);    // h2(t-1)
      vmwait0();
      h_commit(R, smem, tid);
    }
    __syncthreads();
    f32x4 A0 = {0.f,0.f,0.f,0.f}, A1 = A0, A2 = A0;
    mfma_h24(smem, P.Whh2 + wr1 * Hn, rr, lk, A0, A1, A2);   // uses h2P
    if (t >= 1) l1_mfma(P, smem, m, wv, lr, lk);             // l1(t-1) from h2P
    {
      uint4 R[12];
      h_issue(R, h1hiC, h1loC, grow0, tid);    // h1(t), published at bar above
      __syncthreads();                         // h2P reads done
      vmwait0();
      h_commit(R, smem, tid);                  // HOFF := h1(t); persists into phase A(t+1)
    }
    __syncthreads();
    mfma_h24(smem, P.Wih2 + wr1 * Hn, rr, lk, A0, A1, A2);   // uses h1C
    write_gbuf(smem, A0, A1, A2, rf, q, lr, lk);
    __syncthreads();
    cell_do(smem, P.b2s, c2reg, h2hiC, h2loC, grow0, m, tid);
    if (t >= 1) l1_final(P, smem, m, grow0, t - 1, tid);     // a1(t-1) store
    group_bar(P.flags, fbase, m, 2 * t + 2);
  }

  // ===== EPILOGUE: out(510), l1(511)->a1(511), out(511) =====
  {
    uint4 S[4]; uint4 R[12];
    if (m < 8) a1_issue(S, P, grow0, tid);                   // a1(510)
    // t=511: p=1, cell2 wrote parity 0
    h_issue(R, P.h2, P.h2 + HSTR, grow0, tid);               // h2(511)
    vmwait0();
    if (m < 8) a1_commit(S, smem, tid);
    h_commit(R, smem, tid);
  }
  __syncthreads();
  p4b_mfma(P, smem, m, grow0, 510, wv, lr, lk);
  l1_mfma(P, smem, m, wv, lr, lk);
  __syncthreads();
  l1_final(P, smem, m, grow0, 511, tid);
  group_bar(P.flags, fbase, m, 2 * Tn + 1);
  {
    uint4 S[4];
    if (m < 8) { a1_issue(S, P, grow0, tid); vmwait0(); a1_commit(S, smem, tid); }
  }
  __syncthreads();
  p4b_mfma(P, smem, m, grow0, 511, wv, lr, lk);
}

// ---------------- launch ----------------
extern "C" void kernel_launch(void* const* d_in, const int* in_sizes, int n_in,
                              void* d_out, int out_size, void* d_ws, size_t ws_size,
                              hipStream_t stream) {
  const float* x     = (const float*)d_in[0];
  const float* Wih1f = (const float*)d_in[1];
  const float* Whh1f = (const float*)d_in[2];
  const float* bih1  = (const float*)d_in[3];
  const float* bhh1  = (const float*)d_in[4];
  const float* Wih2f = (const float*)d_in[5];
  const float* Whh2f = (const float*)d_in[6];
  const float* bih2  = (const float*)d_in[7];
  const float* bhh2  = (const float*)d_in[8];
  const float* l1wf  = (const float*)d_in[9];
  const float* l1b   = (const float*)d_in[10];
  const float* l2wf  = (const float*)d_in[11];
  const float* l2b   = (const float*)d_in[12];

  char* ws = (char*)d_ws;
  constexpr size_t o_Wih1 = 0;
  constexpr size_t o_Whh1 = o_Wih1 + (size_t)3072 * 128 * 2;
  constexpr size_t o_Wih2 = o_Whh1 + (size_t)3072 * 768 * 2;
  constexpr size_t o_Whh2 = o_Wih2 + (size_t)3072 * 768 * 2;
  constexpr size_t o_l1wb = o_Whh2 + (size_t)3072 * 768 * 2;
  constexpr size_t o_l2wb = o_l1wb + (size_t)512 * 768 * 2;
  constexpr size_t o_b1s  = o_l2wb + (size_t)128 * 512 * 2;
  constexpr size_t o_b2s  = o_b1s + (size_t)3072 * 4;
  constexpr size_t o_h1   = o_b2s + (size_t)3072 * 4;
  constexpr size_t o_h2   = o_h1 + (size_t)4 * 512 * 768 * 2;
  constexpr size_t o_a1hi = o_h2 + (size_t)4 * 512 * 768 * 2;
  constexpr size_t o_flg  = o_a1hi + (size_t)512 * 512 * 2;

  SetupP sp;
  sp.Wih1f = Wih1f; sp.Whh1f = Whh1f; sp.Wih2f = Wih2f; sp.Whh2f = Whh2f;
  sp.l1wf = l1wf; sp.l2wf = l2wf; sp.bih1 = bih1; sp.bhh1 = bhh1; sp.bih2 = bih2; sp.bhh2 = bhh2;
  sp.Wih1 = (unsigned short*)(ws + o_Wih1);
  sp.Whh1 = (unsigned short*)(ws + o_Whh1);
  sp.Wih2 = (unsigned short*)(ws + o_Wih2);
  sp.Whh2 = (unsigned short*)(ws + o_Whh2);
  sp.l1wb = (unsigned short*)(ws + o_l1wb);
  sp.l2wb = (unsigned short*)(ws + o_l2wb);
  sp.b1s  = (float*)(ws + o_b1s);
  sp.b2s  = (float*)(ws + o_b2s);
  sp.h1   = (unsigned short*)(ws + o_h1);
  sp.h2   = (unsigned short*)(ws + o_h2);
  sp.flags = (int*)(ws + o_flg);
  setup_kernel<<<2048, 256, 0, stream>>>(sp);

  MainP mp;
  mp.x = x; mp.l1w_f = l1wf; mp.l1b = l1b; mp.l2b = l2b;
  mp.Wih1 = sp.Wih1; mp.Whh1 = sp.Whh1; mp.Wih2 = sp.Wih2; mp.Whh2 = sp.Whh2;
  mp.l1wb = sp.l1wb; mp.l2wb = sp.l2wb;
  mp.b1s = sp.b1s; mp.b2s = sp.b2s;
  mp.h1 = sp.h1; mp.h2 = sp.h2;
  mp.a1hi = (unsigned short*)(ws + o_a1hi);
  mp.out  = (float*)d_out;
  mp.flags = sp.flags;

  hipFuncSetAttribute((const void*)lstm_main,
                      hipFuncAttributeMaxDynamicSharedMemorySize, SMEM_BYTES);
  lstm_main<<<NB, NT, SMEM_BYTES, stream>>>(mp);
}

// Round 7
// 35060.663 us; speedup vs baseline: 2.7257x; 1.0619x over previous
//
#include <hip/hip_runtime.h>

#define Tn 512
#define Bn 512
#define Fn 128
#define Gn 12
#define Hn 768
#define XW 140
#define D1n 512
#define An 128
#define NT 512
#define NB 256
#define NMEM 16
#define MROWS 32
#define UPM 48

// LDS layout (dynamic, 155648 B)
#define XOFF 0          // x: 32 r x 256B hi + lo at +8192       [0, 16384)
#define HOFF 16384      // h tile 32 x 1536B hi; lo at +49152    [16384, 114688)
#define LBOFF 114688    // l1 partials [2][32][32] f32 = 8KB     [114688, 122880)
#define AGOFF 122880    // gbuf 32x200 f32 (25600B) OR a1 tile 32x1024B (32768B)
#define SMEM_BYTES 155648

using bfrag  = __attribute__((ext_vector_type(8))) short;
using f32x4  = __attribute__((ext_vector_type(4))) float;
using short8 = __attribute__((ext_vector_type(8))) short;
using short4v= __attribute__((ext_vector_type(4))) short;
using float4v= __attribute__((ext_vector_type(4))) float;

static const size_t HSTR = (size_t)Bn * Hn;

__device__ __forceinline__ unsigned short f2bf(float x) {
  union { float f; unsigned int u; } v; v.f = x;
  unsigned int r = v.u + 0x7FFFu + ((v.u >> 16) & 1u);
  return (unsigned short)(r >> 16);
}
__device__ __forceinline__ float bf2f(unsigned short h) {
  union { unsigned int u; float f; } v; v.u = ((unsigned int)h) << 16; return v.f;
}
__device__ __forceinline__ float sigmoid_f(float x) { return 1.f / (1.f + __expf(-x)); }
__device__ __forceinline__ float tanh_f(float x) {
  x = fminf(fmaxf(x, -15.f), 15.f);
  float e = __expf(2.f * x);
  return (e - 1.f) / (e + 1.f);
}
__device__ __forceinline__ f32x4 MFMA(bfrag a, bfrag b, f32x4 c) {
  return __builtin_amdgcn_mfma_f32_16x16x32_bf16(a, b, c, 0, 0, 0);
}

// LLC-direct ops (sc0 sc1: bypass L1+L2, coherent at LLC; no fences needed)
__device__ __forceinline__ void ld16llc(uint4& d, const void* p) {
  asm volatile("global_load_dwordx4 %0, %1, off sc0 sc1" : "=&v"(d) : "v"(p));
}
__device__ __forceinline__ void st8llc(void* p, short4v v) {
  unsigned long long u;
  __builtin_memcpy(&u, &v, 8);
  asm volatile("global_store_dwordx2 %0, %1, off sc0 sc1" :: "v"(p), "v"(u) : "memory");
}
__device__ __forceinline__ void vmwait0() {
  asm volatile("s_waitcnt vmcnt(0)" ::: "memory");
  __builtin_amdgcn_sched_barrier(0);
}

// ---- group barrier: NO cache fence. Each wave drains its sc0sc1 stores (vmcnt),
// then one flag store at LLC; members poll 16 flags at LLC. ----
__device__ __forceinline__ void group_bar(int* flags, int fbase, int member, int target) {
  vmwait0();                               // this wave's LLC stores complete
  __syncthreads();                         // all waves drained
  if (threadIdx.x == 0) {
    __hip_atomic_store(flags + (size_t)(fbase + member) * 32, target,
                       __ATOMIC_RELAXED, __HIP_MEMORY_SCOPE_SYSTEM);
  }
  if (threadIdx.x < NMEM) {
    while (__hip_atomic_load(flags + (size_t)(fbase + threadIdx.x) * 32,
                             __ATOMIC_RELAXED, __HIP_MEMORY_SCOPE_SYSTEM) < target)
      __builtin_amdgcn_s_sleep(1);
  }
  __syncthreads();
}

// ---------------- setup ----------------
struct SetupP {
  const float *Wih1f, *Whh1f, *Wih2f, *Whh2f, *l1wf, *l2wf, *bih1, *bhh1, *bih2, *bhh2;
  unsigned short *Wih1, *Whh1, *Wih2, *Whh2, *l1wb, *l2wb;
  float *b1s, *b2s;
  unsigned short *h1, *h2;
  int* flags;
};

__global__ void setup_kernel(SetupP sp) {
  const size_t gtid = (size_t)blockIdx.x * blockDim.x + threadIdx.x;
  const size_t gs = (size_t)gridDim.x * blockDim.x;
  for (size_t i = gtid; i < 3072u*128u; i += gs) sp.Wih1[i] = f2bf(sp.Wih1f[i]);
  for (size_t i = gtid; i < 3072u*768u; i += gs) sp.Whh1[i] = f2bf(sp.Whh1f[i]);
  for (size_t i = gtid; i < 3072u*768u; i += gs) sp.Wih2[i] = f2bf(sp.Wih2f[i]);
  for (size_t i = gtid; i < 3072u*768u; i += gs) sp.Whh2[i] = f2bf(sp.Whh2f[i]);
  for (size_t i = gtid; i < 512u*768u; i += gs) {
    size_t c = i / 768u, k = i - c * 768u;
    sp.l1wb[i] = f2bf(sp.l1wf[c * 780u + k]);
  }
  for (size_t i = gtid; i < 128u*512u; i += gs) sp.l2wb[i] = f2bf(sp.l2wf[i]);
  for (size_t i = gtid; i < 3072u; i += gs) {
    sp.b1s[i] = sp.bih1[i] + sp.bhh1[i];
    sp.b2s[i] = sp.bih2[i] + sp.bhh2[i];
  }
  for (size_t i = gtid; i < 4u*HSTR; i += gs) { sp.h1[i] = 0; sp.h2[i] = 0; }
  for (size_t i = gtid; i < 8192u; i += gs) sp.flags[i] = 0;
}

// ---------------- main ----------------
struct MainP {
  const float* x;
  const float *l1w_f, *l1b, *l2b;
  const unsigned short *Wih1, *Whh1, *Wih2, *Whh2, *l1wb, *l2wb;
  const float *b1s, *b2s;
  unsigned short *h1, *h2, *a1hi;
  float *out;
  int* flags;
};

__device__ __forceinline__ void stage_x(const MainP& P, char* smem, int t, int grow0, int tid) {
  int r = tid >> 4, c0 = (tid & 15) * 8;
  const float* xp = P.x + ((size_t)t * Bn + grow0 + r) * XW + c0;
  float4v v0 = *(const float4v*)xp;
  float4v v1 = *(const float4v*)(xp + 4);
  short8 hv, lv;
  #pragma unroll
  for (int j = 0; j < 4; ++j) {
    unsigned short h = f2bf(v0[j]); hv[j] = (short)h; lv[j] = (short)f2bf(v0[j] - bf2f(h));
  }
  #pragma unroll
  for (int j = 0; j < 4; ++j) {
    unsigned short h = f2bf(v1[j]); hv[4+j] = (short)h; lv[4+j] = (short)f2bf(v1[j] - bf2f(h));
  }
  int g = tid & 15;
  int off = r * 256 + ((g ^ (r & 7)) << 4);
  *(short8*)(smem + XOFF + off) = hv;
  *(short8*)(smem + XOFF + 8192 + off) = lv;
}

// full 32 x 768 hi/lo tile: 12 x 16B per thread
__device__ __forceinline__ void h_issue(uint4 (&R)[12], const unsigned short* hi,
    const unsigned short* lo, int grow0, int tid) {
  #pragma unroll
  for (int it = 0; it < 12; ++it) {
    int idx = tid + it * NT;           // 0..6143
    int hl = (idx >= 3072) ? 1 : 0;
    int i2 = idx - hl * 3072;
    int r = i2 / 96, gq = i2 - r * 96;
    ld16llc(R[it], (hl ? lo : hi) + (size_t)(grow0 + r) * Hn + gq * 8);
  }
}
__device__ __forceinline__ void h_commit(uint4 (&R)[12], char* smem, int tid) {
  #pragma unroll
  for (int it = 0; it < 12; ++it) {
    int idx = tid + it * NT;
    int hl = (idx >= 3072) ? 1 : 0;
    int i2 = idx - hl * 3072;
    int r = i2 / 96, gq = i2 - r * 96;
    *(uint4*)(smem + HOFF + hl * 49152 + r * 1536 + ((gq ^ (r & 7)) << 4)) = R[it];
  }
}

// a1 tile (hi only): 32 x 512, 4 x 16B per thread
__device__ __forceinline__ void a1_issue(uint4 (&S)[4], const MainP& P, int grow0, int tid) {
  #pragma unroll
  for (int it = 0; it < 4; ++it) {
    int idx = tid + it * NT;
    int r = idx >> 6, gq = idx & 63;
    ld16llc(S[it], P.a1hi + (size_t)(grow0 + r) * D1n + gq * 8);
  }
}
__device__ __forceinline__ void a1_commit(uint4 (&S)[4], char* smem, int tid) {
  #pragma unroll
  for (int it = 0; it < 4; ++it) {
    int idx = tid + it * NT;
    int r = idx >> 6, gq = idx & 63;
    *(uint4*)(smem + AGOFF + r * 1024 + ((gq ^ (r & 7)) << 4)) = S[it];
  }
}

__device__ __forceinline__ void mfma_x4(const char* smem, const unsigned short* bp, int rr, int lk,
                                        f32x4& A0, f32x4& A1, f32x4& A2) {
  const int rsw = rr & 7;
  const char* ax = smem + XOFF + rr * 256;
  #pragma unroll
  for (int kk = 0; kk < 4; ++kk) {
    int kg = kk * 4 + lk;
    int ao = ((kg ^ rsw) << 4);
    bfrag ahi = *(const bfrag*)(ax + ao);
    bfrag alo = *(const bfrag*)(ax + 8192 + ao);
    bfrag b0 = *(const bfrag*)(bp + kk * 32 + lk * 8);
    bfrag b1 = *(const bfrag*)(bp + 16 * Fn + kk * 32 + lk * 8);
    bfrag b2 = *(const bfrag*)(bp + 32 * Fn + kk * 32 + lk * 8);
    A0 = MFMA(ahi, b0, A0); A0 = MFMA(alo, b0, A0);
    A1 = MFMA(ahi, b1, A1); A1 = MFMA(alo, b1, A1);
    A2 = MFMA(ahi, b2, A2); A2 = MFMA(alo, b2, A2);
  }
}

__device__ __forceinline__ void mfma_h24(const char* smem, const unsigned short* bp, int rr, int lk,
                                         f32x4& A0, f32x4& A1, f32x4& A2) {
  const int rsw = rr & 7;
  const char* ah = smem + HOFF + rr * 1536;
  #pragma unroll 6
  for (int kk = 0; kk < 24; ++kk) {
    int kg = kk * 4 + lk;
    int ao = ((kg ^ rsw) << 4);
    bfrag ahi = *(const bfrag*)(ah + ao);
    bfrag alo = *(const bfrag*)(ah + 49152 + ao);
    bfrag b0 = *(const bfrag*)(bp + kk * 32 + lk * 8);
    bfrag b1 = *(const bfrag*)(bp + 16 * Hn + kk * 32 + lk * 8);
    bfrag b2 = *(const bfrag*)(bp + 32 * Hn + kk * 32 + lk * 8);
    A0 = MFMA(ahi, b0, A0); A0 = MFMA(alo, b0, A0);
    A1 = MFMA(ahi, b1, A1); A1 = MFMA(alo, b1, A1);
    A2 = MFMA(ahi, b2, A2); A2 = MFMA(alo, b2, A2);
  }
}

// l1 partial from HOFF (= h2(t-1)); writes LBOFF
__device__ __forceinline__ void l1_mfma(const MainP& P, char* smem, int m,
                                        int wv, int lr, int lk) {
  int nt = wv & 1, mt = (wv >> 1) & 1, kh = wv >> 2;
  f32x4 acc = {0.f,0.f,0.f,0.f};
  const int rr = mt * 16 + lr;
  const int rsw = rr & 7;
  const char* ah = smem + HOFF + rr * 1536;
  const unsigned short* bp = P.l1wb + (size_t)(m * 32 + nt * 16 + lr) * Hn + kh * 384;
  #pragma unroll 4
  for (int kk = 0; kk < 12; ++kk) {
    int kg = (kh * 12 + kk) * 4 + lk;
    int ao = ((kg ^ rsw) << 4);
    bfrag ahi = *(const bfrag*)(ah + ao);
    bfrag alo = *(const bfrag*)(ah + 49152 + ao);
    bfrag bw = *(const bfrag*)(bp + kk * 32 + lk * 8);
    acc = MFMA(ahi, bw, acc); acc = MFMA(alo, bw, acc);
  }
  float* lb = (float*)(smem + LBOFF);
  #pragma unroll
  for (int j = 0; j < 4; ++j)
    lb[(kh * 32 + mt * 16 + lk * 4 + j) * 32 + nt * 16 + lr] = acc[j];
}

// l1 finalize -> a1hi(t1) via LLC store
__device__ __forceinline__ void l1_final(const MainP& P, const char* smem, int m,
                                         int grow0, int t1, int tid) {
  if (tid < 256) {
    int r = tid >> 3, cq = tid & 7;
    int cc = m * 32 + cq * 4;
    const float* lb = (const float*)(smem + LBOFF);
    const float* xg = P.x + ((size_t)t1 * Bn + grow0 + r) * XW + Fn;
    float xgv[Gn];
    #pragma unroll
    for (int qq = 0; qq < Gn; ++qq) xgv[qq] = xg[qq];
    short4v hv;
    #pragma unroll
    for (int j = 0; j < 4; ++j) {
      int c = cq * 4 + j;
      float s = lb[r * 32 + c] + lb[1024 + r * 32 + c] + P.l1b[cc + j];
      const float* wg = P.l1w_f + (size_t)(cc + j) * 780 + 768;
      #pragma unroll
      for (int qq = 0; qq < Gn; ++qq) s += xgv[qq] * wg[qq];
      float a = (s > 0.f) ? 1.0507009873554805f * s
                          : 1.7580993408473766f * (__expf(s) - 1.f);
      hv[j] = (short)f2bf(a);
    }
    st8llc(P.a1hi + (size_t)(grow0 + r) * D1n + cc, hv);
  }
}

__device__ __forceinline__ void write_gbuf(char* smem, const f32x4& A0, const f32x4& A1,
                                           const f32x4& A2, int rf, int q, int lr, int lk) {
  float* gb = (float*)(smem + AGOFF);
  int base = (rf * 16 + lk * 4) * 200 + q * 48 + lr;
  #pragma unroll
  for (int j = 0; j < 4; ++j) {
    gb[base + j * 200]      = A0[j];
    gb[base + j * 200 + 16] = A1[j];
    gb[base + j * 200 + 32] = A2[j];
  }
}

// LSTM cell: h writes via LLC stores (hi+lo)
__device__ __forceinline__ void cell_do(const char* smem, const float* bsum,
    float4v& creg, unsigned short* hhi, unsigned short* hlo,
    int grow0, int m, int tid) {
  if (tid < 384) {
    const float* gb = (const float*)(smem + AGOFF);
    int r = tid / 12, lu0 = (tid - r * 12) * 4;
    short4v hv, lv; float4v cn4;
    #pragma unroll
    for (int j = 0; j < 4; ++j) {
      int lu = lu0 + j;
      int u = m * UPM + lu;
      float gi = gb[r * 200 + lu]       + bsum[u];
      float gf = gb[r * 200 + 48 + lu]  + bsum[Hn + u];
      float gg = gb[r * 200 + 96 + lu]  + bsum[2 * Hn + u];
      float go = gb[r * 200 + 144 + lu] + bsum[3 * Hn + u];
      float cn = sigmoid_f(gf) * creg[j] + sigmoid_f(gi) * tanh_f(gg);
      float hn = sigmoid_f(go) * tanh_f(cn);
      cn4[j] = cn;
      unsigned short h = f2bf(hn);
      hv[j] = (short)h;
      lv[j] = (short)f2bf(hn - bf2f(h));
    }
    creg = cn4;
    size_t idx = (size_t)(grow0 + r) * Hn + m * UPM + lu0;
    st8llc(hhi + idx, hv);
    st8llc(hlo + idx, lv);
  }
}

// l2 -> out(t1): members 0..7, waves 0..1
__device__ __forceinline__ void p4b_mfma(const MainP& P, const char* smem, int m, int grow0,
                                         int t1, int wv, int lr, int lk) {
  if (m < 8 && wv < 2) {
    f32x4 o = {0.f,0.f,0.f,0.f};
    const unsigned short* bp = P.l2wb + (size_t)(m * 16 + lr) * 512;
    const int rr2 = wv * 16 + lr, rsw = rr2 & 7;
    const char* ab = smem + AGOFF + rr2 * 1024;
    #pragma unroll 4
    for (int kk = 0; kk < 16; ++kk) {
      int kg = kk * 4 + lk;
      bfrag ah = *(const bfrag*)(ab + ((kg ^ rsw) << 4));
      bfrag bw = *(const bfrag*)(bp + kk * 32 + lk * 8);
      o = MFMA(ah, bw, o);
    }
    float bb = P.l2b[m * 16 + lr];
    #pragma unroll
    for (int j = 0; j < 4; ++j)
      P.out[((size_t)t1 * Bn + grow0 + wv * 16 + lk * 4 + j) * An + m * 16 + lr] = o[j] + bb;
  }
}

__global__ __launch_bounds__(NT) void lstm_main(MainP P) {
  extern __shared__ char smem[];
  const int tid = threadIdx.x;
  const int bid = blockIdx.x;
  const int lane = tid & 63;
  const int wv = tid >> 6;
  const int lr = lane & 15;
  const int lk = lane >> 4;
  const int m = bid & 15;
  const int gid = bid >> 4;
  const int grow0 = gid * MROWS;
  const int q = wv & 3, rf = wv >> 2;
  const int rr = rf * 16 + lr;
  const int fbase = gid * NMEM;
  const size_t wr1 = (size_t)(q * Hn + m * UPM + lr);

  float4v c1reg = {0.f,0.f,0.f,0.f}, c2reg = {0.f,0.f,0.f,0.f};

  // h1(-1) = 0 in the persistent LDS h tile
  for (int i = tid; i < 24576; i += NT) ((int*)(smem + HOFF))[i] = 0;
  __syncthreads();

  for (int t = 0; t < Tn; ++t) {
    const int p = t & 1;
    unsigned short* h1hiC = P.h1 + (size_t)((p ^ 1) * 2)     * HSTR;
    unsigned short* h1loC = P.h1 + (size_t)((p ^ 1) * 2 + 1) * HSTR;
    const unsigned short* h2hiP = P.h2 + (size_t)(p * 2)     * HSTR;
    const unsigned short* h2loP = P.h2 + (size_t)(p * 2 + 1) * HSTR;
    unsigned short* h2hiC = P.h2 + (size_t)((p ^ 1) * 2)     * HSTR;
    unsigned short* h2loC = P.h2 + (size_t)((p ^ 1) * 2 + 1) * HSTR;

    // ===== PHASE A: [l2 -> out(t-2)] + gates1 + cell1. HOFF = h1(t-1). =====
    const bool doP4 = (t >= 2) && (m < 8);
    uint4 R[12];
    h_issue(R, h2hiP, h2loP, grow0, tid);      // h2(t-1): available since last barrier;
                                               // latency hides under ALL of phase A
    {
      uint4 S[4];
      if (doP4) a1_issue(S, P, grow0, tid);
      stage_x(P, smem, t, grow0, tid);
      __syncthreads();                         // x staged; prev AGOFF readers done
      if (doP4) { vmwait0(); a1_commit(S, smem, tid); }
    }
    __syncthreads();                           // a1 staged
    if (t >= 2) p4b_mfma(P, smem, m, grow0, t - 2, wv, lr, lk);
    {
      f32x4 A0 = {0.f,0.f,0.f,0.f}, A1 = A0, A2 = A0;
      mfma_x4(smem, P.Wih1 + wr1 * Fn, rr, lk, A0, A1, A2);
      mfma_h24(smem, P.Whh1 + wr1 * Hn, rr, lk, A0, A1, A2);
      __syncthreads();                         // all HOFF/AGOFF reads done
      vmwait0();
      h_commit(R, smem, tid);                  // HOFF := h2(t-1) for phase B
      write_gbuf(smem, A0, A1, A2, rf, q, lr, lk);
    }
    __syncthreads();
    cell_do(smem, P.b1s, c1reg, h1hiC, h1loC, grow0, m, tid);  // LLC stores
    group_bar(P.flags, fbase, m, 2 * t + 1);

    // ===== PHASE B: gates2 + cell2 + l1(t-1). HOFF = h2(t-1). =====
    h_issue(R, h1hiC, h1loC, grow0, tid);      // h1(t): published at bar above;
                                               // hides under Whh2 + l1 MFMA
    f32x4 A0 = {0.f,0.f,0.f,0.f}, A1 = A0, A2 = A0;
    mfma_h24(smem, P.Whh2 + wr1 * Hn, rr, lk, A0, A1, A2);     // h2(t-1)
    if (t >= 1) l1_mfma(P, smem, m, wv, lr, lk);               // l1(t-1) partials
    __syncthreads();                           // HOFF reads done
    vmwait0();
    h_commit(R, smem, tid);                    // HOFF := h1(t); persists into A(t+1)
    __syncthreads();
    mfma_h24(smem, P.Wih2 + wr1 * Hn, rr, lk, A0, A1, A2);     // h1(t)
    write_gbuf(smem, A0, A1, A2, rf, q, lr, lk);
    __syncthreads();
    cell_do(smem, P.b2s, c2reg, h2hiC, h2loC, grow0, m, tid);  // LLC stores
    if (t >= 1) l1_final(P, smem, m, grow0, t - 1, tid);       // LLC stores
    group_bar(P.flags, fbase, m, 2 * t + 2);
  }

  // ===== EPILOGUE: out(510), l1(511)->a1(511), out(511) =====
  {
    uint4 S[4]; uint4 R[12];
    if (m < 8) a1_issue(S, P, grow0, tid);                     // a1(510)
    h_issue(R, P.h2, P.h2 + HSTR, grow0, tid);                 // h2(511) (parity 0)
    vmwait0();
    if (m < 8) a1_commit(S, smem, tid);
    h_commit(R, smem, tid);
  }
  __syncthreads();
  p4b_mfma(P, smem, m, grow0, 510, wv, lr, lk);
  l1_mfma(P, smem, m, wv, lr, lk);
  __syncthreads();
  l1_final(P, smem, m, grow0, 511, tid);
  group_bar(P.flags, fbase, m, 2 * Tn + 1);
  {
    uint4 S[4];
    if (m < 8) { a1_issue(S, P, grow0, tid); vmwait0(); a1_commit(S, smem, tid); }
  }
  __syncthreads();
  p4b_mfma(P, smem, m, grow0, 511, wv, lr, lk);
}

// ---------------- launch ----------------
extern "C" void kernel_launch(void* const* d_in, const int* in_sizes, int n_in,
                              void* d_out, int out_size, void* d_ws, size_t ws_size,
                              hipStream_t stream) {
  const float* x     = (const float*)d_in[0];
  const float* Wih1f = (const float*)d_in[1];
  const float* Whh1f = (const float*)d_in[2];
  const float* bih1  = (const float*)d_in[3];
  const float* bhh1  = (const float*)d_in[4];
  const float* Wih2f = (const float*)d_in[5];
  const float* Whh2f = (const float*)d_in[6];
  const float* bih2  = (const float*)d_in[7];
  const float* bhh2  = (const float*)d_in[8];
  const float* l1wf  = (const float*)d_in[9];
  const float* l1b   = (const float*)d_in[10];
  const float* l2wf  = (const float*)d_in[11];
  const float* l2b   = (const float*)d_in[12];

  char* ws = (char*)d_ws;
  constexpr size_t o_Wih1 = 0;
  constexpr size_t o_Whh1 = o_Wih1 + (size_t)3072 * 128 * 2;
  constexpr size_t o_Wih2 = o_Whh1 + (size_t)3072 * 768 * 2;
  constexpr size_t o_Whh2 = o_Wih2 + (size_t)3072 * 768 * 2;
  constexpr size_t o_l1wb = o_Whh2 + (size_t)3072 * 768 * 2;
  constexpr size_t o_l2wb = o_l1wb + (size_t)512 * 768 * 2;
  constexpr size_t o_b1s  = o_l2wb + (size_t)128 * 512 * 2;
  constexpr size_t o_b2s  = o_b1s + (size_t)3072 * 4;
  constexpr size_t o_h1   = o_b2s + (size_t)3072 * 4;
  constexpr size_t o_h2   = o_h1 + (size_t)4 * 512 * 768 * 2;
  constexpr size_t o_a1hi = o_h2 + (size_t)4 * 512 * 768 * 2;
  constexpr size_t o_flg  = o_a1hi + (size_t)512 * 512 * 2;

  SetupP sp;
  sp.Wih1f = Wih1f; sp.Whh1f = Whh1f; sp.Wih2f = Wih2f; sp.Whh2f = Whh2f;
  sp.l1wf = l1wf; sp.l2wf = l2wf; sp.bih1 = bih1; sp.bhh1 = bhh1; sp.bih2 = bih2; sp.bhh2 = bhh2;
  sp.Wih1 = (unsigned short*)(ws + o_Wih1);
  sp.Whh1 = (unsigned short*)(ws + o_Whh1);
  sp.Wih2 = (unsigned short*)(ws + o_Wih2);
  sp.Whh2 = (unsigned short*)(ws + o_Whh2);
  sp.l1wb = (unsigned short*)(ws + o_l1wb);
  sp.l2wb = (unsigned short*)(ws + o_l2wb);
  sp.b1s  = (float*)(ws + o_b1s);
  sp.b2s  = (float*)(ws + o_b2s);
  sp.h1   = (unsigned short*)(ws + o_h1);
  sp.h2   = (unsigned short*)(ws + o_h2);
  sp.flags = (int*)(ws + o_flg);
  setup_kernel<<<2048, 256, 0, stream>>>(sp);

  MainP mp;
  mp.x = x; mp.l1w_f = l1wf; mp.l1b = l1b; mp.l2b = l2b;
  mp.Wih1 = sp.Wih1; mp.Whh1 = sp.Whh1; mp.Wih2 = sp.Wih2; mp.Whh2 = sp.Whh2;
  mp.l1wb = sp.l1wb; mp.l2wb = sp.l2wb;
  mp.b1s = sp.b1s; mp.b2s = sp.b2s;
  mp.h1 = sp.h1; mp.h2 = sp.h2;
  mp.a1hi = (unsigned short*)(ws + o_a1hi);
  mp.out  = (float*)d_out;
  mp.flags = sp.flags;

  hipFuncSetAttribute((const void*)lstm_main,
                      hipFuncAttributeMaxDynamicSharedMemorySize, SMEM_BYTES);
  lstm_main<<<NB, NT, SMEM_BYTES, stream>>>(mp);
}

// Round 9
// 33639.450 us; speedup vs baseline: 2.8409x; 1.0422x over previous
//
#include <hip/hip_runtime.h>

#define Tn 512
#define Bn 512
#define Fn 128
#define Gn 12
#define Hn 768
#define XW 140
#define D1n 512
#define An 128
#define NT 512
#define NB 512
#define NMEM 16
#define MROWS 16
#define UPM 48

// LDS layout (dynamic, 77824 B) -> 2 blocks/CU (2x77824 = 155648 <= 163840)
#define XOFF 0        // x hi [16][256B] + lo at +4096            [0, 8192)
#define HOFF 8192     // h hi [16][1536B] 24KB + lo at +24576     [8192, 57344)
#define LBOFF 57344   // l1 partials [2][16][32] f32 = 4KB        [57344, 61440)
#define AGOFF 61440   // a1 [16][1024B] 16KB | gbuf [4][16][48]   [61440, 77824)
#define SMEM_BYTES 77824

using bfrag  = __attribute__((ext_vector_type(8))) short;
using f32x4  = __attribute__((ext_vector_type(4))) float;
using short8 = __attribute__((ext_vector_type(8))) short;
using short4v= __attribute__((ext_vector_type(4))) short;
using float4v= __attribute__((ext_vector_type(4))) float;

static const size_t HSTR = (size_t)Bn * Hn;
static const size_t A1SZ = (size_t)Bn * D1n;

__device__ __forceinline__ unsigned short f2bf(float x) {
  union { float f; unsigned int u; } v; v.f = x;
  unsigned int r = v.u + 0x7FFFu + ((v.u >> 16) & 1u);
  return (unsigned short)(r >> 16);
}
__device__ __forceinline__ float bf2f(unsigned short h) {
  union { unsigned int u; float f; } v; v.u = ((unsigned int)h) << 16; return v.f;
}
__device__ __forceinline__ float sigmoid_f(float x) { return 1.f / (1.f + __expf(-x)); }
__device__ __forceinline__ float tanh_f(float x) {
  x = fminf(fmaxf(x, -15.f), 15.f);
  float e = __expf(2.f * x);
  return (e - 1.f) / (e + 1.f);
}
__device__ __forceinline__ f32x4 MFMA(bfrag a, bfrag b, f32x4 c) {
  return __builtin_amdgcn_mfma_f32_16x16x32_bf16(a, b, c, 0, 0, 0);
}

__device__ __forceinline__ void st8llc(void* p, short4v v) {
  unsigned long long u;
  __builtin_memcpy(&u, &v, 8);
  asm volatile("global_store_dwordx2 %0, %1, off sc0 sc1" :: "v"(p), "v"(u) : "memory");
}
__device__ __forceinline__ void vmwait0() {
  asm volatile("s_waitcnt vmcnt(0)" ::: "memory");
  __builtin_amdgcn_sched_barrier(0);
}

// group barrier (R7-proven): drain LLC stores, flag store, poll 16 flags
__device__ __forceinline__ void group_bar(int* flags, int fbase, int member, int target) {
  vmwait0();
  __syncthreads();
  if (threadIdx.x == 0) {
    __hip_atomic_store(flags + (size_t)(fbase + member) * 32, target,
                       __ATOMIC_RELAXED, __HIP_MEMORY_SCOPE_SYSTEM);
  }
  if (threadIdx.x < NMEM) {
    while (__hip_atomic_load(flags + (size_t)(fbase + threadIdx.x) * 32,
                             __ATOMIC_RELAXED, __HIP_MEMORY_SCOPE_SYSTEM) < target)
      __builtin_amdgcn_s_sleep(1);
  }
  __syncthreads();
}

// ---------------- setup ----------------
struct SetupP {
  const float *Wih1f, *Whh1f, *Wih2f, *Whh2f, *l1wf, *l2wf, *bih1, *bhh1, *bih2, *bhh2;
  unsigned short *Wih1, *Whh1, *Wih2, *Whh2, *l1wb, *l2wb;
  float *b1s, *b2s;
  unsigned short *h1, *h2;
  int* flags;
};

__global__ void setup_kernel(SetupP sp) {
  const size_t gtid = (size_t)blockIdx.x * blockDim.x + threadIdx.x;
  const size_t gs = (size_t)gridDim.x * blockDim.x;
  for (size_t i = gtid; i < 3072u*128u; i += gs) sp.Wih1[i] = f2bf(sp.Wih1f[i]);
  for (size_t i = gtid; i < 3072u*768u; i += gs) sp.Whh1[i] = f2bf(sp.Whh1f[i]);
  for (size_t i = gtid; i < 3072u*768u; i += gs) sp.Wih2[i] = f2bf(sp.Wih2f[i]);
  for (size_t i = gtid; i < 3072u*768u; i += gs) sp.Whh2[i] = f2bf(sp.Whh2f[i]);
  for (size_t i = gtid; i < 512u*768u; i += gs) {
    size_t c = i / 768u, k = i - c * 768u;
    sp.l1wb[i] = f2bf(sp.l1wf[c * 780u + k]);
  }
  for (size_t i = gtid; i < 128u*512u; i += gs) sp.l2wb[i] = f2bf(sp.l2wf[i]);
  for (size_t i = gtid; i < 3072u; i += gs) {
    sp.b1s[i] = sp.bih1[i] + sp.bhh1[i];
    sp.b2s[i] = sp.bih2[i] + sp.bhh2[i];
  }
  for (size_t i = gtid; i < 4u*HSTR; i += gs) { sp.h1[i] = 0; sp.h2[i] = 0; }
  for (size_t i = gtid; i < 16384u; i += gs) sp.flags[i] = 0;
}

// ---------------- main ----------------
struct MainP {
  const float* x;
  const float *l1w_f, *l1b, *l2b;
  const unsigned short *Wih1, *Whh1, *Wih2, *Whh2, *l1wb, *l2wb;
  const float *b1s, *b2s;
  unsigned short *h1, *h2, *a1hi;
  float *out;
  int* flags;
};

__device__ __forceinline__ void stage_x(const MainP& P, char* smem, int t, int grow0, int tid) {
  if (tid < 256) {
    int r = tid >> 4, g = tid & 15;
    const float* xp = P.x + ((size_t)t * Bn + grow0 + r) * XW + g * 8;
    float4v v0 = *(const float4v*)xp;
    float4v v1 = *(const float4v*)(xp + 4);
    short8 hv, lv;
    #pragma unroll
    for (int j = 0; j < 4; ++j) {
      unsigned short h = f2bf(v0[j]); hv[j] = (short)h; lv[j] = (short)f2bf(v0[j] - bf2f(h));
    }
    #pragma unroll
    for (int j = 0; j < 4; ++j) {
      unsigned short h = f2bf(v1[j]); hv[4+j] = (short)h; lv[4+j] = (short)f2bf(v1[j] - bf2f(h));
    }
    int off = r * 256 + ((g ^ (r & 7)) << 4);
    *(short8*)(smem + XOFF + off) = hv;
    *(short8*)(smem + XOFF + 4096 + off) = lv;
  }
}

// SPILL-PROOF fused stage: one asm block {6 loads + vmcnt(0)}, LDS stores right after.
__device__ __forceinline__ void stage_h_fused(char* smem, const unsigned short* hi,
    const unsigned short* lo, int grow0, int tid) {
  const unsigned short *p0,*p1,*p2,*p3,*p4,*p5;
  int o0,o1,o2,o3,o4,o5;
#define HADDR(IT, P, O) { \
    int idx = tid + IT * NT; \
    int hl = (idx >= 1536) ? 1 : 0; \
    int i2 = idx - hl * 1536; \
    int r = i2 / 96, gq = i2 - r * 96; \
    P = (hl ? lo : hi) + (size_t)(grow0 + r) * Hn + gq * 8; \
    O = HOFF + hl * 24576 + r * 1536 + ((gq ^ (r & 7)) << 4); }
  HADDR(0, p0, o0) HADDR(1, p1, o1) HADDR(2, p2, o2)
  HADDR(3, p3, o3) HADDR(4, p4, o4) HADDR(5, p5, o5)
#undef HADDR
  uint4 R0,R1,R2,R3,R4,R5;
  asm volatile(
    "global_load_dwordx4 %0, %6, off sc0 sc1\n\t"
    "global_load_dwordx4 %1, %7, off sc0 sc1\n\t"
    "global_load_dwordx4 %2, %8, off sc0 sc1\n\t"
    "global_load_dwordx4 %3, %9, off sc0 sc1\n\t"
    "global_load_dwordx4 %4, %10, off sc0 sc1\n\t"
    "global_load_dwordx4 %5, %11, off sc0 sc1\n\t"
    "s_waitcnt vmcnt(0)"
    : "=&v"(R0),"=&v"(R1),"=&v"(R2),"=&v"(R3),"=&v"(R4),"=&v"(R5)
    : "v"(p0),"v"(p1),"v"(p2),"v"(p3),"v"(p4),"v"(p5)
    : "memory");
  *(uint4*)(smem + o0) = R0;
  *(uint4*)(smem + o1) = R1;
  *(uint4*)(smem + o2) = R2;
  *(uint4*)(smem + o3) = R3;
  *(uint4*)(smem + o4) = R4;
  *(uint4*)(smem + o5) = R5;
}

__device__ __forceinline__ void stage_a1_fused(char* smem, const unsigned short* a1p,
                                               int grow0, int tid) {
  const unsigned short *p0, *p1;
  int o0, o1;
  {
    int r = tid >> 6, gq = tid & 63;
    p0 = a1p + (size_t)(grow0 + r) * D1n + gq * 8;
    o0 = AGOFF + r * 1024 + ((gq ^ (r & 7)) << 4);
  }
  {
    int idx = tid + NT;
    int r = idx >> 6, gq = idx & 63;
    p1 = a1p + (size_t)(grow0 + r) * D1n + gq * 8;
    o1 = AGOFF + r * 1024 + ((gq ^ (r & 7)) << 4);
  }
  uint4 S0, S1;
  asm volatile(
    "global_load_dwordx4 %0, %2, off sc0 sc1\n\t"
    "global_load_dwordx4 %1, %3, off sc0 sc1\n\t"
    "s_waitcnt vmcnt(0)"
    : "=&v"(S0), "=&v"(S1) : "v"(p0), "v"(p1) : "memory");
  *(uint4*)(smem + o0) = S0;
  *(uint4*)(smem + o1) = S1;
}

__device__ __forceinline__ void mfma_x4(const char* smem, const unsigned short* bp, int lr, int lk,
                                        f32x4& A0, f32x4& A1, f32x4& A2) {
  const int rsw = lr & 7;
  const char* ax = smem + XOFF + lr * 256;
  #pragma unroll
  for (int kk = 0; kk < 4; ++kk) {
    int kg = kk * 4 + lk;
    int ao = ((kg ^ rsw) << 4);
    bfrag ahi = *(const bfrag*)(ax + ao);
    bfrag alo = *(const bfrag*)(ax + 4096 + ao);
    bfrag b0 = *(const bfrag*)(bp + kk * 32 + lk * 8);
    bfrag b1 = *(const bfrag*)(bp + 16 * Fn + kk * 32 + lk * 8);
    bfrag b2 = *(const bfrag*)(bp + 32 * Fn + kk * 32 + lk * 8);
    A0 = MFMA(ahi, b0, A0); A0 = MFMA(alo, b0, A0);
    A1 = MFMA(ahi, b1, A1); A1 = MFMA(alo, b1, A1);
    A2 = MFMA(ahi, b2, A2); A2 = MFMA(alo, b2, A2);
  }
}

__device__ __forceinline__ void mfma_h24(const char* smem, const unsigned short* bp, int lr, int lk,
                                         f32x4& A0, f32x4& A1, f32x4& A2) {
  const int rsw = lr & 7;
  const char* ah = smem + HOFF + lr * 1536;
  #pragma unroll 6
  for (int kk = 0; kk < 24; ++kk) {
    int kg = kk * 4 + lk;
    int ao = ((kg ^ rsw) << 4);
    bfrag ahi = *(const bfrag*)(ah + ao);
    bfrag alo = *(const bfrag*)(ah + 24576 + ao);
    bfrag b0 = *(const bfrag*)(bp + kk * 32 + lk * 8);
    bfrag b1 = *(const bfrag*)(bp + 16 * Hn + kk * 32 + lk * 8);
    bfrag b2 = *(const bfrag*)(bp + 32 * Hn + kk * 32 + lk * 8);
    A0 = MFMA(ahi, b0, A0); A0 = MFMA(alo, b0, A0);
    A1 = MFMA(ahi, b1, A1); A1 = MFMA(alo, b1, A1);
    A2 = MFMA(ahi, b2, A2); A2 = MFMA(alo, b2, A2);
  }
}

// l1 partial from HOFF (= h2(t-2)); hw0 waves: q -> (nt = q&1, kh = q>>1)
__device__ __forceinline__ void l1_mfma(const MainP& P, char* smem, int m,
                                        int q, int lr, int lk) {
  int nt = q & 1, kh = q >> 1;
  f32x4 acc = {0.f,0.f,0.f,0.f};
  const int rsw = lr & 7;
  const char* ah = smem + HOFF + lr * 1536;
  const unsigned short* bp = P.l1wb + (size_t)(m * 32 + nt * 16 + lr) * Hn + kh * 384;
  #pragma unroll 4
  for (int kk = 0; kk < 12; ++kk) {
    int kg = (kh * 12 + kk) * 4 + lk;
    int ao = ((kg ^ rsw) << 4);
    bfrag ahi = *(const bfrag*)(ah + ao);
    bfrag alo = *(const bfrag*)(ah + 24576 + ao);
    bfrag bw = *(const bfrag*)(bp + kk * 32 + lk * 8);
    acc = MFMA(ahi, bw, acc); acc = MFMA(alo, bw, acc);
  }
  float* lb = (float*)(smem + LBOFF);
  #pragma unroll
  for (int j = 0; j < 4; ++j)
    lb[(kh * 16 + lk * 4 + j) * 32 + nt * 16 + lr] = acc[j];
}

// l1 finalize -> a1hi(t1); threads 256..383
__device__ __forceinline__ void l1_final(const MainP& P, const char* smem, int m,
                                         int grow0, int t1, int tid) {
  if (tid >= 256 && tid < 384) {
    int idx = tid - 256;
    int r = idx >> 3, cq = idx & 7;
    int cc = m * 32 + cq * 4;
    const float* lb = (const float*)(smem + LBOFF);
    const float* xg = P.x + ((size_t)t1 * Bn + grow0 + r) * XW + Fn;
    float xgv[Gn];
    #pragma unroll
    for (int qq = 0; qq < Gn; ++qq) xgv[qq] = xg[qq];
    short4v hv;
    #pragma unroll
    for (int j = 0; j < 4; ++j) {
      int c = cq * 4 + j;
      float s = lb[r * 32 + c] + lb[(16 + r) * 32 + c] + P.l1b[cc + j];
      const float* wg = P.l1w_f + (size_t)(cc + j) * 780 + 768;
      #pragma unroll
      for (int qq = 0; qq < Gn; ++qq) s += xgv[qq] * wg[qq];
      float a = (s > 0.f) ? 1.0507009873554805f * s
                          : 1.7580993408473766f * (__expf(s) - 1.f);
      hv[j] = (short)f2bf(a);
    }
    unsigned short* a1w = P.a1hi + (size_t)(t1 & 1) * A1SZ;
    st8llc(a1w + (size_t)(grow0 + r) * D1n + cc, hv);
  }
}

// gbuf [4][16][48] f32 at AGOFF
__device__ __forceinline__ void write_gbuf(char* smem, const f32x4& A0, const f32x4& A1,
                                           const f32x4& A2, int q, int lr, int lk) {
  float* gb = (float*)(smem + AGOFF);
  int base = (q * 16 + lk * 4) * 48 + lr;
  #pragma unroll
  for (int j = 0; j < 4; ++j) {
    gb[base + j * 48]      = A0[j];
    gb[base + j * 48 + 16] = A1[j];
    gb[base + j * 48 + 32] = A2[j];
  }
}

// LSTM cell (tid<192): 16 rows x 48 units; publish h via LLC stores
__device__ __forceinline__ void cell_do(const char* smem, const float* bsum,
    float4v& creg, unsigned short* hhi, unsigned short* hlo,
    int grow0, int m, int tid) {
  if (tid < 192) {
    const float* gb = (const float*)(smem + AGOFF);
    int r = tid / 12, lu0 = (tid - r * 12) * 4;
    short4v hv, lv; float4v cn4;
    #pragma unroll
    for (int j = 0; j < 4; ++j) {
      int lu = lu0 + j;
      int u = m * UPM + lu;
      float gi = gb[(0*16 + r) * 48 + lu] + bsum[u];
      float gf = gb[(1*16 + r) * 48 + lu] + bsum[Hn + u];
      float gg = gb[(2*16 + r) * 48 + lu] + bsum[2 * Hn + u];
      float go = gb[(3*16 + r) * 48 + lu] + bsum[3 * Hn + u];
      float cn = sigmoid_f(gf) * creg[j] + sigmoid_f(gi) * tanh_f(gg);
      float hn = sigmoid_f(go) * tanh_f(cn);
      cn4[j] = cn;
      unsigned short h = f2bf(hn);
      hv[j] = (short)h;
      lv[j] = (short)f2bf(hn - bf2f(h));
    }
    creg = cn4;
    size_t idx = (size_t)(grow0 + r) * Hn + m * UPM + lu0;
    st8llc(hhi + idx, hv);
    st8llc(hlo + idx, lv);
  }
}

// l2 -> out(t1): m<8, wave 0 only; reads a1 tile at AGOFF
__device__ __forceinline__ void p4b_mfma(const MainP& P, const char* smem, int m, int grow0,
                                         int t1, int lr, int lk) {
  f32x4 o = {0.f,0.f,0.f,0.f};
  const unsigned short* bp = P.l2wb + (size_t)(m * 16 + lr) * 512;
  const int rsw = lr & 7;
  const char* ab = smem + AGOFF + lr * 1024;
  #pragma unroll 4
  for (int kk = 0; kk < 16; ++kk) {
    int kg = kk * 4 + lk;
    bfrag ah = *(const bfrag*)(ab + ((kg ^ rsw) << 4));
    bfrag bw = *(const bfrag*)(bp + kk * 32 + lk * 8);
    o = MFMA(ah, bw, o);
  }
  float bb = P.l2b[m * 16 + lr];
  #pragma unroll
  for (int j = 0; j < 4; ++j)
    P.out[((size_t)t1 * Bn + grow0 + lk * 4 + j) * An + m * 16 + lr] = o[j] + bb;
}

__global__ __launch_bounds__(NT, 4) void lstm_main(MainP P) {
  extern __shared__ char smem[];
  const int tid = threadIdx.x;
  const int bid = blockIdx.x;
  const int lane = tid & 63;
  const int wv = tid >> 6;
  const int lr = lane & 15;
  const int lk = lane >> 4;
  const int m = bid & 15;
  const int gid = bid >> 4;          // 0..31
  const int grow0 = gid * MROWS;
  const int q = wv & 3;
  const int hw = wv >> 2;            // 0: layer1+head duties, 1: layer2 duties
  const int fbase = gid * NMEM;
  const size_t wr1 = (size_t)(q * Hn + m * UPM + lr);

  float4v c1reg = {0.f,0.f,0.f,0.f}, c2reg = {0.f,0.f,0.f,0.f};

  for (int t = 0; t <= Tn + 2; ++t) {
    const int r1 = (t - 1) & 1;          // h1(t-1) read parity
    const int w1 = t & 1;                // h1(t) write parity
    const int r2 = t & 1;                // h2(t-2) read parity
    const int w2 = (t - 1) & 1;          // h2(t-1) write parity
    const unsigned short* h1hiR = P.h1 + (size_t)(r1 * 2)     * HSTR;
    const unsigned short* h1loR = P.h1 + (size_t)(r1 * 2 + 1) * HSTR;
    unsigned short* h1hiW = P.h1 + (size_t)(w1 * 2)     * HSTR;
    unsigned short* h1loW = P.h1 + (size_t)(w1 * 2 + 1) * HSTR;
    const unsigned short* h2hiR = P.h2 + (size_t)(r2 * 2)     * HSTR;
    const unsigned short* h2loR = P.h2 + (size_t)(r2 * 2 + 1) * HSTR;
    unsigned short* h2hiW = P.h2 + (size_t)(w2 * 2)     * HSTR;
    unsigned short* h2loW = P.h2 + (size_t)(w2 * 2 + 1) * HSTR;

    const bool doG1 = (t < Tn);
    const bool doH1 = (t <= Tn);
    const bool doG2 = (t >= 1 && t <= Tn);
    const bool doH2 = (t >= 1 && t <= Tn + 1);
    const bool doL1 = (t >= 2 && t <= Tn + 1);
    const bool doP4 = (t >= 3) && (m < 8);

    // ---- top: stage x(t), h1(t-1) -> HOFF, a1(t-3) -> AGOFF (all fused, spill-proof) ----
    if (doG1) stage_x(P, smem, t, grow0, tid);
    if (doH1) stage_h_fused(smem, h1hiR, h1loR, grow0, tid);
    if (doP4) stage_a1_fused(smem, P.a1hi + (size_t)((t - 1) & 1) * A1SZ, grow0, tid);
    __syncthreads();

    // ---- l2 -> out(t-3) on wave 0, concurrent with phase1 MFMAs ----
    if (doP4 && wv == 0) p4b_mfma(P, smem, m, grow0, t - 3, lr, lk);

    // ---- phase1: HOFF = h1(t-1) ----
    f32x4 A0 = {0.f,0.f,0.f,0.f}, A1 = A0, A2 = A0;
    if (hw == 0) {
      if (doG1) {
        mfma_x4(smem, P.Wih1 + wr1 * Fn, lr, lk, A0, A1, A2);
        mfma_h24(smem, P.Whh1 + wr1 * Hn, lr, lk, A0, A1, A2);
      }
    } else {
      if (doG2) mfma_h24(smem, P.Wih2 + wr1 * Hn, lr, lk, A0, A1, A2);
    }
    __syncthreads();                            // HOFF + AGOFF(a1) reads done

    if (doH2) stage_h_fused(smem, h2hiR, h2loR, grow0, tid);   // HOFF := h2(t-2)
    __syncthreads();

    // ---- phase2: HOFF = h2(t-2) ----
    if (hw == 0) {
      if (doL1) l1_mfma(P, smem, m, q, lr, lk);
    } else {
      if (doG2) mfma_h24(smem, P.Whh2 + wr1 * Hn, lr, lk, A0, A1, A2);
    }
    __syncthreads();                            // phase2 HOFF reads + LB writes done

    // ---- tail: cells + head finalize ----
    if (hw == 0 && doG1) write_gbuf(smem, A0, A1, A2, q, lr, lk);
    __syncthreads();
    if (doG1) cell_do(smem, P.b1s, c1reg, h1hiW, h1loW, grow0, m, tid);
    __syncthreads();                            // cell1 gbuf reads done
    if (hw == 1 && doG2) write_gbuf(smem, A0, A1, A2, q, lr, lk);
    __syncthreads();
    if (doG2) cell_do(smem, P.b2s, c2reg, h2hiW, h2loW, grow0, m, tid);
    if (doL1) l1_final(P, smem, m, grow0, t - 2, tid);
    group_bar(P.flags, fbase, m, t + 1);
  }
}

// ---------------- launch ----------------
extern "C" void kernel_launch(void* const* d_in, const int* in_sizes, int n_in,
                              void* d_out, int out_size, void* d_ws, size_t ws_size,
                              hipStream_t stream) {
  const float* x     = (const float*)d_in[0];
  const float* Wih1f = (const float*)d_in[1];
  const float* Whh1f = (const float*)d_in[2];
  const float* bih1  = (const float*)d_in[3];
  const float* bhh1  = (const float*)d_in[4];
  const float* Wih2f = (const float*)d_in[5];
  const float* Whh2f = (const float*)d_in[6];
  const float* bih2  = (const float*)d_in[7];
  const float* bhh2  = (const float*)d_in[8];
  const float* l1wf  = (const float*)d_in[9];
  const float* l1b   = (const float*)d_in[10];
  const float* l2wf  = (const float*)d_in[11];
  const float* l2b   = (const float*)d_in[12];

  char* ws = (char*)d_ws;
  constexpr size_t o_Wih1 = 0;
  constexpr size_t o_Whh1 = o_Wih1 + (size_t)3072 * 128 * 2;
  constexpr size_t o_Wih2 = o_Whh1 + (size_t)3072 * 768 * 2;
  constexpr size_t o_Whh2 = o_Wih2 + (size_t)3072 * 768 * 2;
  constexpr size_t o_l1wb = o_Whh2 + (size_t)3072 * 768 * 2;
  constexpr size_t o_l2wb = o_l1wb + (size_t)512 * 768 * 2;
  constexpr size_t o_b1s  = o_l2wb + (size_t)128 * 512 * 2;
  constexpr size_t o_b2s  = o_b1s + (size_t)3072 * 4;
  constexpr size_t o_h1   = o_b2s + (size_t)3072 * 4;
  constexpr size_t o_h2   = o_h1 + (size_t)4 * 512 * 768 * 2;
  constexpr size_t o_a1hi = o_h2 + (size_t)4 * 512 * 768 * 2;
  constexpr size_t o_flg  = o_a1hi + (size_t)2 * 512 * 512 * 2;

  SetupP sp;
  sp.Wih1f = Wih1f; sp.Whh1f = Whh1f; sp.Wih2f = Wih2f; sp.Whh2f = Whh2f;
  sp.l1wf = l1wf; sp.l2wf = l2wf; sp.bih1 = bih1; sp.bhh1 = bhh1; sp.bih2 = bih2; sp.bhh2 = bhh2;
  sp.Wih1 = (unsigned short*)(ws + o_Wih1);
  sp.Whh1 = (unsigned short*)(ws + o_Whh1);
  sp.Wih2 = (unsigned short*)(ws + o_Wih2);
  sp.Whh2 = (unsigned short*)(ws + o_Whh2);
  sp.l1wb = (unsigned short*)(ws + o_l1wb);
  sp.l2wb = (unsigned short*)(ws + o_l2wb);
  sp.b1s  = (float*)(ws + o_b1s);
  sp.b2s  = (float*)(ws + o_b2s);
  sp.h1   = (unsigned short*)(ws + o_h1);
  sp.h2   = (unsigned short*)(ws + o_h2);
  sp.flags = (int*)(ws + o_flg);
  setup_kernel<<<2048, 256, 0, stream>>>(sp);

  MainP mp;
  mp.x = x; mp.l1w_f = l1wf; mp.l1b = l1b; mp.l2b = l2b;
  mp.Wih1 = sp.Wih1; mp.Whh1 = sp.Whh1; mp.Wih2 = sp.Wih2; mp.Whh2 = sp.Whh2;
  mp.l1wb = sp.l1wb; mp.l2wb = sp.l2wb;
  mp.b1s = sp.b1s; mp.b2s = sp.b2s;
  mp.h1 = sp.h1; mp.h2 = sp.h2;
  mp.a1hi = (unsigned short*)(ws + o_a1hi);
  mp.out  = (float*)d_out;
  mp.flags = sp.flags;

  hipFuncSetAttribute((const void*)lstm_main,
                      hipFuncAttributeMaxDynamicSharedMemorySize, SMEM_BYTES);
  lstm_main<<<NB, NT, SMEM_BYTES, stream>>>(mp);
}